// Round 8
// baseline (1033.379 us; speedup 1.0000x reference)
//
#include <hip/hip_runtime.h>
#include <hip/hip_bf16.h>
#include <cstddef>

#define N_NODES 10000
#define KTOP 30
#define CAP 2048     // max CSR row length
#define CANDCAP 512
#define NQ4 (N_NODES / 4)   // 2500 float4 per row
#define NTILE 79     // ceil(10000/128)

typedef _Float16 f16x8 __attribute__((ext_vector_type(8)));
typedef float f32x4 __attribute__((ext_vector_type(4)));

// ---------------- fused split pass 1: features rows + W1^T + W2^T ----------------
// split(v): hi = f16(v*256), lo = f16(v*256 - hi); exact 2^8 scale.
__global__ __launch_bounds__(256) void fused_split1(const float* __restrict__ feat,
                                                    _Float16* __restrict__ fhi,
                                                    _Float16* __restrict__ flo,
                                                    const float* __restrict__ W1,
                                                    _Float16* __restrict__ w1hi,
                                                    _Float16* __restrict__ w1lo,
                                                    const float* __restrict__ W2,
                                                    _Float16* __restrict__ w2hi,
                                                    _Float16* __restrict__ w2lo) {
    int b = blockIdx.x;
    int t = threadIdx.x;
    if (b < 10000) {
        int i = b * 256 + t;
        float v = feat[i] * 256.0f;
        _Float16 h = (_Float16)v;
        fhi[i] = h;
        flo[i] = (_Float16)(v - (float)h);
    } else if (b < 10256) {
        int n = b - 10000;
        float v = W1[t * 256 + n] * 256.0f;
        _Float16 h = (_Float16)v;
        w1hi[n * 256 + t] = h;
        w1lo[n * 256 + t] = (_Float16)(v - (float)h);
    } else {
        int n = b - 10256;
        float v = W2[t * 256 + n] * 256.0f;
        _Float16 h = (_Float16)v;
        w2hi[n * 256 + t] = h;
        w2lo[n * 256 + t] = (_Float16)(v - (float)h);
    }
}

// ---------------- fused split pass 2: x rows + Wg1^T (128 cols) ----------------
__global__ __launch_bounds__(256) void fused_split2(const float* __restrict__ x,
                                                    _Float16* __restrict__ xhi,
                                                    _Float16* __restrict__ xlo,
                                                    const float* __restrict__ Wg1,
                                                    _Float16* __restrict__ ghi,
                                                    _Float16* __restrict__ glo) {
    int b = blockIdx.x;
    int t = threadIdx.x;
    if (b < 10000) {
        int i = b * 256 + t;
        float v = x[i] * 256.0f;
        _Float16 h = (_Float16)v;
        xhi[i] = h;
        xlo[i] = (_Float16)(v - (float)h);
    } else {
        int n = b - 10000;
        float v = Wg1[t * 128 + n] * 256.0f;
        _Float16 h = (_Float16)v;
        ghi[n * 256 + t] = h;
        glo[n * 256 + t] = (_Float16)(v - (float)h);
    }
}

// ---------------- row normalize, numpy-pairwise-exact semantics ----------------
__global__ __launch_bounds__(256) void rownorm_np_kernel(const float* __restrict__ h,
                                                         _Float16* __restrict__ hhi,
                                                         _Float16* __restrict__ hlo) {
    __shared__ float row[256];
    __shared__ float denom_sh;
    int r = blockIdx.x;
    int t = threadIdx.x;
    const float* p = h + (size_t)r * 256;
    row[t] = p[t];
    __syncthreads();
    if (t < 16) {
        int half = t >> 3;
        int j = t & 7;
        const float* a = row + half * 128 + j;
        float rr = __fmul_rn(a[0], a[0]);
        #pragma unroll
        for (int i = 1; i < 16; i++) {
            rr = __fadd_rn(rr, __fmul_rn(a[i * 8], a[i * 8]));
        }
        #pragma unroll
        for (int off = 1; off <= 8; off <<= 1) {
            rr = __fadd_rn(rr, __shfl_xor(rr, off, 64));
        }
        if (t == 0) { denom_sh = __fadd_rn(__fsqrt_rn(rr), 1e-8f); }
    }
    __syncthreads();
    float v = __fdiv_rn(row[t], denom_sh);
    float sc = v * 256.0f;                 // exact (power-of-2 scale)
    _Float16 hv = (_Float16)sc;            // RNE to fp16
    float rem = sc - (float)hv;            // exact (Sterbenz-range)
    hhi[(size_t)r * 256 + t] = hv;
    hlo[(size_t)r * 256 + t] = (_Float16)rem;
}

// ---------------- global_load_lds helper ----------------
__device__ __forceinline__ void gload16(const void* g, void* l) {
    __builtin_amdgcn_global_load_lds(
        (const __attribute__((address_space(1))) unsigned int*)g,
        (__attribute__((address_space(3))) unsigned int*)l, 16, 0, 0);
}

// ---------------- S tile GEMM via fp16-split MFMA, double-buffered pipeline ----------------
// Emits per-(row, col-tile) maxes of relu(S) into TM[10000][80]. Mirror writes
// use float4 (4 consecutive rr per (i,j)).
__global__ __launch_bounds__(256) void gemm_s_f16(const _Float16* __restrict__ hi,
                                                  const _Float16* __restrict__ lo,
                                                  float* __restrict__ S,
                                                  float* __restrict__ TM) {
    int rb = blockIdx.y * 128;
    int cb = blockIdx.x * 128;
    if (cb < rb) { return; }
    __shared__ __align__(16) unsigned short Hs[2][16384];  // 2 x 32 KB (A at 0, B at 8192)
    int t = threadIdx.x;
    int w = t >> 6;
    int lane = t & 63;
    int wr = w >> 1, wc = w & 1;          // wave -> 64x64 quadrant
    int lrow = lane & 15, lk = lane >> 4; // mfma A/B fragment mapping
    int lr8 = lane >> 3, ls8 = lane & 7;  // staging: 8 rows x 8 phys slots per 1KB chunk

    int slog = ls8 ^ lr8;                  // logical slot this lane sources
    const char* srcp = (slog < 4) ? (const char*)hi : (const char*)lo;
    int koff = (slog & 3) * 16;            // 16B k-slot within the stage's 64B range
    int cbase = w * 8;

    f32x4 acc[4][4];
    #pragma unroll
    for (int i = 0; i < 4; i++) {
        #pragma unroll
        for (int j = 0; j < 4; j++) {
            f32x4 z = {0.f, 0.f, 0.f, 0.f};
            acc[i][j] = z;
        }
    }

    auto STAGE = [&](int sidx, int b) {
        int kb = sidx * 64;                // byte offset of stage's k-range (32 halves)
        #pragma unroll
        for (int tt = 0; tt < 8; tt++) {
            int c = cbase + tt;            // chunk 0..31
            int rl = ((c & 15) << 3) + lr8;
            int node = ((c >> 4) ? cb : rb) + rl;
            if (node > N_NODES - 1) { node = N_NODES - 1; }
            gload16(srcp + (size_t)node * 512 + kb + koff, &Hs[b][c << 9]);
        }
    };

    STAGE(0, 0);
    #pragma unroll 1
    for (int s = 0; s < 8; s++) {
        int b = s & 1;
        if (s < 7) { STAGE(s + 1, b ^ 1); }
        __builtin_amdgcn_sched_barrier(0);
        if (s < 7) { asm volatile("s_waitcnt vmcnt(8)" ::: "memory"); }
        else       { asm volatile("s_waitcnt vmcnt(0)" ::: "memory"); }
        __builtin_amdgcn_s_barrier();
        __builtin_amdgcn_sched_barrier(0);
        f16x8 ah[4], al[4], bh[4], bl[4];
        #pragma unroll
        for (int i = 0; i < 4; i++) {
            int ar = wr * 64 + i * 16 + lrow;
            int br = wc * 64 + i * 16 + lrow;
            int ra7 = ar & 7, rb7 = br & 7;
            ah[i] = *(const f16x8*)&Hs[b][ar * 64 + ((lk ^ ra7) << 3)];
            al[i] = *(const f16x8*)&Hs[b][ar * 64 + (((lk + 4) ^ ra7) << 3)];
            bh[i] = *(const f16x8*)&Hs[b][8192 + br * 64 + ((lk ^ rb7) << 3)];
            bl[i] = *(const f16x8*)&Hs[b][8192 + br * 64 + (((lk + 4) ^ rb7) << 3)];
        }
        #pragma unroll
        for (int i = 0; i < 4; i++) {
            #pragma unroll
            for (int j = 0; j < 4; j++) {
                acc[i][j] = __builtin_amdgcn_mfma_f32_16x16x32_f16(ah[i], bh[j], acc[i][j], 0, 0, 0);
                acc[i][j] = __builtin_amdgcn_mfma_f32_16x16x32_f16(ah[i], bl[j], acc[i][j], 0, 0, 0);
                acc[i][j] = __builtin_amdgcn_mfma_f32_16x16x32_f16(al[i], bh[j], acc[i][j], 0, 0, 0);
            }
        }
        __builtin_amdgcn_sched_barrier(0);
        __builtin_amdgcn_s_barrier();
    }

    const float inv = 1.0f / 65536.0f;  // undo 2^8 * 2^8 operand scaling (exact)

    // ---- per-(row, tile) maxes: Hs is dead (post trailing barrier) -> scratch.
    {
        float* red = (float*)Hs;       // [0..255] rowpart [wc][128]; [256..511] colpart [wr][128]
        float rm[4][4];
        #pragma unroll
        for (int i = 0; i < 4; i++) {
            #pragma unroll
            for (int q = 0; q < 4; q++) {
                float m = fmaxf(fmaxf(acc[i][0][q], acc[i][1][q]),
                                fmaxf(acc[i][2][q], acc[i][3][q]));
                #pragma unroll
                for (int off = 1; off <= 8; off <<= 1) { m = fmaxf(m, __shfl_xor(m, off, 64)); }
                rm[i][q] = m;
            }
        }
        if ((lane & 15) == 0) {
            #pragma unroll
            for (int i = 0; i < 4; i++) {
                #pragma unroll
                for (int q = 0; q < 4; q++) {
                    red[wc * 128 + wr * 64 + i * 16 + lk * 4 + q] = rm[i][q];
                }
            }
        }
        float cm[4];
        #pragma unroll
        for (int j = 0; j < 4; j++) {
            float m = acc[0][j][0];
            #pragma unroll
            for (int i = 0; i < 4; i++) {
                #pragma unroll
                for (int q = 0; q < 4; q++) {
                    if (i + q) { m = fmaxf(m, acc[i][j][q]); }
                }
            }
            m = fmaxf(m, __shfl_xor(m, 16, 64));
            m = fmaxf(m, __shfl_xor(m, 32, 64));
            cm[j] = m;
        }
        if (lk == 0) {
            #pragma unroll
            for (int j = 0; j < 4; j++) {
                red[256 + wr * 128 + wc * 64 + j * 16 + lrow] = cm[j];
            }
        }
        __syncthreads();
        if (t < 128) {
            float rmx = fmaxf(red[t], red[128 + t]) * inv;
            int gr = rb + t;
            if (gr < N_NODES) { TM[(size_t)gr * 80 + (cb >> 7)] = fmaxf(rmx, 0.f); }
            float cmx = fmaxf(red[256 + t], red[384 + t]) * inv;
            int gc = cb + t;
            if (gc < N_NODES) { TM[(size_t)gc * 80 + (rb >> 7)] = fmaxf(cmx, 0.f); }
        }
    }

    // epilogue: C/D frag layout col = lane&15, row = (lane>>4)*4 + reg.
    #pragma unroll
    for (int i = 0; i < 4; i++) {
        int rrb = rb + wr * 64 + i * 16 + lk * 4;
        #pragma unroll
        for (int j = 0; j < 4; j++) {
            int cc = cb + wc * 64 + j * 16 + lrow;
            if (cc >= N_NODES) { continue; }
            float4 mv;
            float* mp = &mv.x;
            #pragma unroll
            for (int q = 0; q < 4; q++) {
                float v = fmaxf(acc[i][j][q] * inv, 0.f);
                mp[q] = v;
                int rr = rrb + q;
                if (rr < N_NODES) { S[(size_t)rr * N_NODES + cc] = v; }
            }
            if (rrb + 3 < N_NODES) {
                *(float4*)(S + (size_t)cc * N_NODES + rrb) = mv;
            } else {
                #pragma unroll
                for (int q = 0; q < 4; q++) {
                    int rr = rrb + q;
                    if (rr < N_NODES) { S[(size_t)cc * N_NODES + rr] = mp[q]; }
                }
            }
        }
    }
}

// ---------------- generic 128-tile GEMM via fp16-split MFMA ----------------
template<int MODE>
__global__ __launch_bounds__(256) void gemm_mlp(const _Float16* __restrict__ ahi,
                                                const _Float16* __restrict__ alo,
                                                const _Float16* __restrict__ bhi,
                                                const _Float16* __restrict__ blo,
                                                _Float16* __restrict__ chi,
                                                _Float16* __restrict__ clo,
                                                float* __restrict__ cf,
                                                const float* __restrict__ bias,
                                                int on) {
    int rb = blockIdx.y * 128;
    int cb = blockIdx.x * 128;
    __shared__ __align__(16) unsigned short Hs[32768];  // 64 KB
    int t = threadIdx.x;
    int w = t >> 6;
    int lane = t & 63;
    int wr = w >> 1, wc = w & 1;
    int lrow = lane & 15, lk = lane >> 4;
    int lr8 = lane >> 3, ls8 = lane & 7;
    int koffb = ((ls8 ^ lr8) << 4);

    f32x4 acc[4][4];
    #pragma unroll
    for (int i = 0; i < 4; i++) {
        #pragma unroll
        for (int j = 0; j < 4; j++) {
            f32x4 z = {0.f, 0.f, 0.f, 0.f};
            acc[i][j] = z;
        }
    }

    const char* ahp = (const char*)ahi;
    const char* alp = (const char*)alo;
    const char* bhp = (const char*)bhi;
    const char* blp = (const char*)blo;

    #pragma unroll 1
    for (int ks = 0; ks < 4; ks++) {
        int k0b = ks * 128;
        #pragma unroll
        for (int tt = 0; tt < 4; tt++) {
            int c = w * 4 + tt;
            int rowloc = c * 8 + lr8;
            int na = rb + rowloc; if (na > N_NODES - 1) { na = N_NODES - 1; }
            int nb = cb + rowloc;              // Wt rows always valid
            size_t offA = (size_t)na * 512 + k0b + koffb;
            size_t offB = (size_t)nb * 512 + k0b + koffb;
            gload16(ahp + offA, &Hs[0     + c * 512]);
            gload16(alp + offA, &Hs[8192  + c * 512]);
            gload16(bhp + offB, &Hs[16384 + c * 512]);
            gload16(blp + offB, &Hs[24576 + c * 512]);
        }
        __builtin_amdgcn_s_waitcnt(0);
        __syncthreads();
        #pragma unroll 1
        for (int kk = 0; kk < 2; kk++) {
            f16x8 ah[4], al[4], bh[4], bl[4];
            #pragma unroll
            for (int i = 0; i < 4; i++) {
                int ar = wr * 64 + i * 16 + lrow;
                int br = wc * 64 + i * 16 + lrow;
                int ps = ((kk * 4 + lk) ^ (lrow & 7)) * 8;
                ah[i] = *(const f16x8*)&Hs[0     + ar * 64 + ps];
                al[i] = *(const f16x8*)&Hs[8192  + ar * 64 + ps];
                bh[i] = *(const f16x8*)&Hs[16384 + br * 64 + ps];
                bl[i] = *(const f16x8*)&Hs[24576 + br * 64 + ps];
            }
            #pragma unroll
            for (int i = 0; i < 4; i++) {
                #pragma unroll
                for (int j = 0; j < 4; j++) {
                    acc[i][j] = __builtin_amdgcn_mfma_f32_16x16x32_f16(ah[i], bh[j], acc[i][j], 0, 0, 0);
                    acc[i][j] = __builtin_amdgcn_mfma_f32_16x16x32_f16(ah[i], bl[j], acc[i][j], 0, 0, 0);
                    acc[i][j] = __builtin_amdgcn_mfma_f32_16x16x32_f16(al[i], bh[j], acc[i][j], 0, 0, 0);
                }
            }
        }
        __syncthreads();
    }

    const float inv = 1.0f / 65536.0f;
    #pragma unroll
    for (int i = 0; i < 4; i++) {
        int rrb = rb + wr * 64 + i * 16 + lk * 4;
        #pragma unroll
        for (int j = 0; j < 4; j++) {
            int cc = cb + wc * 64 + j * 16 + lrow;
            if (cc >= on && MODE == 0) { continue; }
            #pragma unroll
            for (int q = 0; q < 4; q++) {
                int rr = rrb + q;
                if (rr >= N_NODES) { continue; }
                if (MODE == 1) {
                    float sv = fmaxf(acc[i][j][q], 0.f) * (1.0f / 256.0f);
                    _Float16 hv = (_Float16)sv;
                    chi[(size_t)rr * 256 + cc] = hv;
                    clo[(size_t)rr * 256 + cc] = (_Float16)(sv - (float)hv);
                } else {
                    float v = acc[i][j][q] * inv;
                    if (bias != nullptr) { v += bias[cc]; }
                    cf[(size_t)rr * on + cc] = v;
                }
            }
        }
    }
}

// ---------------- order-statistic-pruned exact top-30, ties -> HIGHEST index ----------------
// 256 threads/row. thr = 30th-largest tile-max (exact superset bound) via rank.
// Collection over 4 waves; selection on wave 0. Fuses degrees (deg pre-zeroed).
// Does NOT zero S (standalone zero_fill handles the Adj zero).
__global__ __launch_bounds__(256) void topk_sel_kernel(float* __restrict__ S,
                                                       const float* __restrict__ TM,
                                                       float* __restrict__ tv,
                                                       int* __restrict__ ti,
                                                       float* __restrict__ deg) {
    __shared__ float cv[CANDCAP];
    __shared__ int ci[CANDCAP];
    __shared__ float tmv[NTILE];
    __shared__ int cntSh;
    __shared__ float thrSh;
    __shared__ float wv[4];
    __shared__ int wi[4];
    int t = threadIdx.x;
    int w = t >> 6;
    int lane = t & 63;
    int r = blockIdx.x;
    float* row = S + (size_t)r * N_NODES;
    const float* trow = TM + (size_t)r * 80;
    if (t == 0) { cntSh = 0; }
    if (t < NTILE) { tmv[t] = trow[t]; }
    __syncthreads();

    // thr by rank: lane ranks its <=2 tile-max values against all 79
    if (t < 64) {
        float v0 = tmv[lane];
        float v1 = (lane + 64 < NTILE) ? tmv[lane + 64] : -3.f;
        int rk0 = 0, rk1 = 0;
        for (int j = 0; j < NTILE; j++) {
            float vj = tmv[j];
            if (vj > v0 || (vj == v0 && j > lane)) { rk0++; }
            if (vj > v1 || (vj == v1 && j > lane + 64)) { rk1++; }
        }
        if (rk0 == KTOP - 1) { thrSh = v0; }
        if (lane + 64 < NTILE && rk1 == KTOP - 1) { thrSh = v1; }
    }
    __syncthreads();
    float thr = thrSh;

    // collection: wave w handles tiles w, w+4, ... (parallel, no insertion)
    for (int tt = w; tt < NTILE; tt += 4) {
        if (tmv[tt] < thr) { continue; }
        int c0 = tt * 128 + lane;
        int c1 = c0 + 64;
        float x0 = (c0 < N_NODES) ? row[c0] : -1.f;
        float x1 = (c1 < N_NODES) ? row[c1] : -1.f;
        if (x0 >= thr) {
            int p = atomicAdd(&cntSh, 1);
            if (p < CANDCAP) { cv[p] = x0; ci[p] = c0; }
        }
        if (x1 >= thr) {
            int p = atomicAdd(&cntSh, 1);
            if (p < CANDCAP) { cv[p] = x1; ci[p] = c1; }
        }
    }
    __syncthreads();
    int ncand = cntSh;
    bool fb = (ncand > CANDCAP) || (ncand < KTOP);

    if (fb) {
        // exact fallback over the intact row (value desc, index desc), 256t
        float rs = 0.f;
        for (int k = 0; k < KTOP; k++) {
            float bv = -1.f;
            int bi = -1;
            for (int j = t; j < N_NODES; j += 256) {
                float v = row[j];
                if (v >= bv) { bv = v; bi = j; }
            }
            #pragma unroll
            for (int off = 32; off > 0; off >>= 1) {
                float ov = __shfl_down(bv, off, 64);
                int oi = __shfl_down(bi, off, 64);
                if (ov > bv || (ov == bv && oi > bi)) { bv = ov; bi = oi; }
            }
            if (lane == 0) { wv[w] = bv; wi[w] = bi; }
            __syncthreads();
            if (t == 0) {
                float fv = wv[0];
                int fi = wi[0];
                for (int q = 1; q < 4; q++) {
                    if (wv[q] > fv || (wv[q] == fv && wi[q] > fi)) { fv = wv[q]; fi = wi[q]; }
                }
                tv[r * KTOP + k] = fv;
                ti[r * KTOP + k] = fi;
                atomicAdd(deg + fi, 0.5f * fv);
                rs += fv;
                row[fi] = -1.f;      // removed from later rounds; zero_fill wipes S after
            }
            __syncthreads();
        }
        if (t == 0) { atomicAdd(deg + r, 0.5f * rs); }
        return;
    }

    // selection: wave 0 only, barrier-free (intra-wave LDS is program-ordered)
    if (t < 64) {
        float rs = 0.f;
        if (ncand <= 128) {
            float v0 = -2.f, v1 = -2.f;
            int i0 = -1, i1 = -1;
            if (lane < ncand) { v0 = cv[lane]; i0 = ci[lane]; }
            if (lane + 64 < ncand) { v1 = cv[lane + 64]; i1 = ci[lane + 64]; }
            for (int k = 0; k < KTOP; k++) {
                bool sel1 = (v1 > v0) || (v1 == v0 && i1 > i0);
                float bv = sel1 ? v1 : v0;
                int bi = sel1 ? i1 : i0;
                #pragma unroll
                for (int m = 32; m > 0; m >>= 1) {
                    float ov = __shfl_xor(bv, m, 64);
                    int oi = __shfl_xor(bi, m, 64);
                    if (ov > bv || (ov == bv && oi > bi)) { bv = ov; bi = oi; }
                }
                if (lane == 0) {
                    tv[r * KTOP + k] = bv;
                    ti[r * KTOP + k] = bi;
                    atomicAdd(deg + bi, 0.5f * bv);
                    rs += bv;
                }
                if (i0 == bi) { v0 = -2.f; }
                if (i1 == bi) { v1 = -2.f; }
            }
        } else {
            for (int k = 0; k < KTOP; k++) {
                float bv = -2.f;
                int bi = -1;
                int bq = -1;
                for (int q = lane; q < ncand; q += 64) {
                    float v = cv[q];
                    int idx = ci[q];
                    if (v > bv || (v == bv && idx > bi)) { bv = v; bi = idx; bq = q; }
                }
                #pragma unroll
                for (int m = 32; m > 0; m >>= 1) {
                    float ov = __shfl_xor(bv, m, 64);
                    int oi = __shfl_xor(bi, m, 64);
                    int oq = __shfl_xor(bq, m, 64);
                    if (ov > bv || (ov == bv && oi > bi)) { bv = ov; bi = oi; bq = oq; }
                }
                if (lane == 0) {
                    tv[r * KTOP + k] = bv;
                    ti[r * KTOP + k] = bi;
                    atomicAdd(deg + bi, 0.5f * bv);
                    rs += bv;
                    cv[bq] = -2.f;
                }
            }
        }
        if (lane == 0) { atomicAdd(deg + r, 0.5f * rs); }
    }
}

// ---------------- zero fill ----------------
__global__ __launch_bounds__(256) void zero_fill(float4* __restrict__ p, unsigned int n4) {
    unsigned int i = blockIdx.x * 256u + threadIdx.x;
    unsigned int stride = gridDim.x * 256u;
    float4 z = {0.f, 0.f, 0.f, 0.f};
    for (; i < n4; i += stride) { p[i] = z; }
}

// ---------------- CSR build (+ optional fused dense Adj scatter); dis inlined ----------------
template<int WRITE_ADJ>
__global__ __launch_bounds__(256) void csr_adj(const float* __restrict__ tv,
                                               const int* __restrict__ ti,
                                               const float* __restrict__ deg,
                                               int* __restrict__ cnt,
                                               int* __restrict__ nbr,
                                               float* __restrict__ wgt,
                                               float* __restrict__ Adj) {
    int e = blockIdx.x * 256 + threadIdx.x;
    if (e >= N_NODES * KTOP) { return; }
    int i = e / KTOP;
    int j = ti[e];
    float v = tv[e];
    float vrev = 0.f;
    bool mutual = false;
    const int* tj = ti + (size_t)j * KTOP;
    const float* tvj = tv + (size_t)j * KTOP;
    for (int k = 0; k < KTOP; k++) {
        if (tj[k] == i) { vrev = tvj[k]; mutual = true; }
    }
    float dgi = deg[i];
    float dgj = deg[j];
    float di = dgi > 0.f ? 1.f / sqrtf(fmaxf(dgi, 1e-8f)) : 0.f;
    float dj = dgj > 0.f ? 1.f / sqrtf(fmaxf(dgj, 1e-8f)) : 0.f;
    float w = 0.5f * (v + vrev) * di * dj;
    int p = atomicAdd(cnt + i, 1);
    if (p < CAP) {
        nbr[(size_t)i * CAP + p] = j;
        wgt[(size_t)i * CAP + p] = w;
    }
    if (!mutual) {
        int p2 = atomicAdd(cnt + j, 1);
        if (p2 < CAP) {
            nbr[(size_t)j * CAP + p2] = i;
            wgt[(size_t)j * CAP + p2] = w;
        }
    }
    if (WRITE_ADJ) {
        Adj[(size_t)i * N_NODES + j] = w;
        Adj[(size_t)j * N_NODES + i] = w;
    }
}

// ---------------- Adj scatter (fallback path only); dis inlined ----------------
__global__ __launch_bounds__(256) void adj_scatter(const float* __restrict__ tv,
                                                   const int* __restrict__ ti,
                                                   const float* __restrict__ deg,
                                                   float* __restrict__ Adj) {
    int e = blockIdx.x * 256 + threadIdx.x;
    if (e >= N_NODES * KTOP) { return; }
    int i = e / KTOP;
    int j = ti[e];
    float v = tv[e];
    float vrev = 0.f;
    const int* tj = ti + (size_t)j * KTOP;
    const float* tvj = tv + (size_t)j * KTOP;
    for (int k = 0; k < KTOP; k++) {
        if (tj[k] == i) { vrev = tvj[k]; }
    }
    float dgi = deg[i];
    float dgj = deg[j];
    float di = dgi > 0.f ? 1.f / sqrtf(fmaxf(dgi, 1e-8f)) : 0.f;
    float dj = dgj > 0.f ? 1.f / sqrtf(fmaxf(dgj, 1e-8f)) : 0.f;
    float w = 0.5f * (v + vrev) * di * dj;
    Adj[(size_t)i * N_NODES + j] = w;
    Adj[(size_t)j * N_NODES + i] = w;
}

// ---------------- gather SpMM, 128 channels, relu fused (4x ILP) ----------------
__global__ __launch_bounds__(256) void gather128(const int* __restrict__ cnt,
                                                 const int* __restrict__ nbr,
                                                 const float* __restrict__ wgt,
                                                 const float* __restrict__ T,
                                                 float* __restrict__ Y) {
    int node = blockIdx.x * 2 + (threadIdx.x >> 7);
    int c = threadIdx.x & 127;
    if (node >= N_NODES) { return; }
    int n = cnt[node];
    if (n > CAP) { n = CAP; }
    const int* nb = nbr + (size_t)node * CAP;
    const float* wg = wgt + (size_t)node * CAP;
    float a0 = 0.f, a1 = 0.f, a2 = 0.f, a3 = 0.f;
    int k = 0;
    for (; k + 4 <= n; k += 4) {
        int4 j = *(const int4*)(nb + k);
        float4 w = *(const float4*)(wg + k);
        float t0 = T[(size_t)j.x * 128 + c];
        float t1 = T[(size_t)j.y * 128 + c];
        float t2 = T[(size_t)j.z * 128 + c];
        float t3 = T[(size_t)j.w * 128 + c];
        a0 = fmaf(w.x, t0, a0);
        a1 = fmaf(w.y, t1, a1);
        a2 = fmaf(w.z, t2, a2);
        a3 = fmaf(w.w, t3, a3);
    }
    for (; k < n; k++) { a0 = fmaf(wg[k], T[(size_t)nb[k] * 128 + c], a0); }
    float acc = (a0 + a1) + (a2 + a3);
    Y[(size_t)node * 128 + c] = fmaxf(acc, 0.f);
}

// ---------------- y1[M,128] @ Wg2[128,16] + bg2 -> t2[M,16] ----------------
__global__ __launch_bounds__(256) void gemm16(const float* __restrict__ y1,
                                              const float* __restrict__ Wg2,
                                              const float* __restrict__ bg2,
                                              float* __restrict__ out) {
    __shared__ float Ws[2048];
    __shared__ float Ys[16 * 132];
    int t = threadIdx.x;
    int n0 = blockIdx.x * 16;
    for (int i = t; i < 2048; i += 256) {
        Ws[i] = Wg2[i];
        int rr = i >> 7, cc = i & 127;
        int node = n0 + rr;
        if (node > N_NODES - 1) { node = N_NODES - 1; }
        Ys[rr * 132 + cc] = y1[(size_t)node * 128 + cc];
    }
    __syncthreads();
    int nn = t >> 4;
    int c = t & 15;
    int node = n0 + nn;
    if (node >= N_NODES) { return; }
    const float* yr = Ys + nn * 132;
    float acc = 0.f;
    #pragma unroll 4
    for (int k = 0; k < 128; k++) {
        acc = fmaf(yr[k], Ws[k * 16 + c], acc);
    }
    out[(size_t)node * 16 + c] = acc + bg2[c];
}

// ---------------- gather SpMM, 16 channels (4x ILP) ----------------
__global__ __launch_bounds__(256) void gather16(const int* __restrict__ cnt,
                                                const int* __restrict__ nbr,
                                                const float* __restrict__ wgt,
                                                const float* __restrict__ T,
                                                float* __restrict__ Y) {
    int node = blockIdx.x * 16 + (threadIdx.x >> 4);
    int c = threadIdx.x & 15;
    if (node >= N_NODES) { return; }
    int n = cnt[node];
    if (n > CAP) { n = CAP; }
    const int* nb = nbr + (size_t)node * CAP;
    const float* wg = wgt + (size_t)node * CAP;
    float a0 = 0.f, a1 = 0.f, a2 = 0.f, a3 = 0.f;
    int k = 0;
    for (; k + 4 <= n; k += 4) {
        int4 j = *(const int4*)(nb + k);
        float4 w = *(const float4*)(wg + k);
        float t0 = T[(size_t)j.x * 16 + c];
        float t1 = T[(size_t)j.y * 16 + c];
        float t2 = T[(size_t)j.z * 16 + c];
        float t3 = T[(size_t)j.w * 16 + c];
        a0 = fmaf(w.x, t0, a0);
        a1 = fmaf(w.y, t1, a1);
        a2 = fmaf(w.z, t2, a2);
        a3 = fmaf(w.w, t3, a3);
    }
    for (; k < n; k++) { a0 = fmaf(wg[k], T[(size_t)nb[k] * 16 + c], a0); }
    Y[(size_t)node * 16 + c] = (a0 + a1) + (a2 + a3);
}

extern "C" void kernel_launch(void* const* d_in, const int* in_sizes, int n_in,
                              void* d_out, int out_size, void* d_ws, size_t ws_size,
                              hipStream_t stream) {
    const float* features = (const float*)d_in[0];
    const float* x   = (const float*)d_in[1];
    const float* W1  = (const float*)d_in[2];
    const float* W2  = (const float*)d_in[3];
    const float* Wg1 = (const float*)d_in[4];
    const float* bg1 = (const float*)d_in[5];
    const float* Wg2 = (const float*)d_in[6];
    const float* bg2 = (const float*)d_in[7];

    float* ws = (float*)d_ws;
    // region A [0, 2.56M) floats: fsp -> hbuf -> tmax -> xsp
    // region B [2.56M, 5.12M) floats: h1sp -> Hhi/Hlo -> t1 | y1
    float* hbuf = ws;
    float* tmax = ws;                          // 800,000 f (10000 x 80), over dead hbuf
    float* tv   = ws + 5120000;               // 300,000 f
    int*   ti   = (int*)(ws + 5420000);       // 300,000 i
    float* deg  = ws + 5720000;               // 10,000 f
    int*   cnt  = (int*)(ws + 5730000);       // 10,000 i (adjacent to deg: one memset)
    float* t2   = ws + 5740000;               // 160,000 f (W-splits live here early)
    float* t1   = ws + 2560000;               // Hhi region, after gemm_s dead
    float* y1   = ws + 3840000;               // Hlo region, after gemm_s dead

    _Float16* fsphi = (_Float16*)ws;
    _Float16* fsplo = fsphi + 2560000;
    _Float16* xsphi = (_Float16*)ws;                    // after tmax dead (post topk)
    _Float16* xsplo = xsphi + 2560000;
    _Float16* h1hi = (_Float16*)(ws + 2560000);
    _Float16* h1lo = h1hi + 2560000;
    _Float16* Hhi  = (_Float16*)(ws + 2560000);
    _Float16* Hlo  = Hhi + 2560000;
    _Float16* W1thi = (_Float16*)(ws + 5740000);        // 65,536 halves each
    _Float16* W1tlo = W1thi + 65536;
    _Float16* W2thi = W1thi + 131072;
    _Float16* W2tlo = W1thi + 196608;
    _Float16* Wg1thi = (_Float16*)(ws + 5740000);       // reuse after MLP chain (128x256)
    _Float16* Wg1tlo = Wg1thi + 32768;

    float* out_f = (float*)d_out;             // 160,000 f32
    float* Adj   = out_f + 160000;            // 1e8 f32 = 400 MB
    float* Sbuf  = Adj;                       // S until topk

    // CSR placement: workspace if it fits, else alias Adj (zero+scatter at end)
    size_t csr_off = 5910000;                                  // floats
    size_t csr_need = (csr_off + (size_t)N_NODES * CAP * 2) * sizeof(float);
    bool csr_in_ws = ws_size >= csr_need;
    int*   nbr = csr_in_ws ? (int*)(ws + csr_off) : (int*)Adj;
    float* wgt = csr_in_ws ? (float*)(ws + csr_off + (size_t)N_NODES * CAP)
                           : (float*)(Adj + (size_t)N_NODES * CAP);

    // ---- splits (one launch) + MLP chain via fp16-split MFMA ----
    fused_split1<<<dim3(10512), dim3(256), 0, stream>>>(
        features, fsphi, fsplo, W1, W1thi, W1tlo, W2, W2thi, W2tlo);
    gemm_mlp<1><<<dim3(2, 79), dim3(256), 0, stream>>>(
        fsphi, fsplo, W1thi, W1tlo, h1hi, h1lo, (float*)nullptr, (const float*)nullptr, 256);
    gemm_mlp<0><<<dim3(2, 79), dim3(256), 0, stream>>>(
        h1hi, h1lo, W2thi, W2tlo, (_Float16*)nullptr, (_Float16*)nullptr, hbuf,
        (const float*)nullptr, 256);
    rownorm_np_kernel<<<dim3(N_NODES), dim3(256), 0, stream>>>(hbuf, Hhi, Hlo);

    // ---- S (triangle + mirror) + tile maxes; pruned exact top-30 + degrees ----
    gemm_s_f16<<<dim3(79, 79), dim3(256), 0, stream>>>(Hhi, Hlo, Sbuf, tmax);
    hipMemsetAsync(deg, 0, 2 * N_NODES * sizeof(float), stream);   // deg + cnt
    topk_sel_kernel<<<dim3(N_NODES), dim3(256), 0, stream>>>(Sbuf, tmax, tv, ti, deg);

    // ---- Adj zero (S dead) when CSR lives in ws ----
    if (csr_in_ws) {
        zero_fill<<<dim3(2048), dim3(256), 0, stream>>>(
            (float4*)Adj, (unsigned int)((size_t)N_NODES * N_NODES / 4));
    }

    // ---- x + Wg1 splits (one launch; tmax + W1t/W2t dead) + GCN layer-1 GEMM ----
    fused_split2<<<dim3(10128), dim3(256), 0, stream>>>(
        x, xsphi, xsplo, Wg1, Wg1thi, Wg1tlo);
    gemm_mlp<0><<<dim3(1, 79), dim3(256), 0, stream>>>(
        xsphi, xsplo, Wg1thi, Wg1tlo, (_Float16*)nullptr, (_Float16*)nullptr, t1, bg1, 128);

    // ---- CSR build (+ fused Adj scatter when CSR lives in ws); dis inlined ----
    int eblocks = (N_NODES * KTOP + 255) / 256;
    if (csr_in_ws) {
        csr_adj<1><<<dim3(eblocks), dim3(256), 0, stream>>>(tv, ti, deg, cnt, nbr, wgt, Adj);
    } else {
        csr_adj<0><<<dim3(eblocks), dim3(256), 0, stream>>>(tv, ti, deg, cnt, nbr, wgt, Adj);
    }

    // ---- GCN layers via gather SpMM ----
    gather128<<<dim3(N_NODES / 2), dim3(256), 0, stream>>>(cnt, nbr, wgt, t1, y1);
    gemm16<<<dim3(625), dim3(256), 0, stream>>>(y1, Wg2, bg2, t2);
    gather16<<<dim3((N_NODES + 15) / 16), dim3(256), 0, stream>>>(cnt, nbr, wgt, t2, out_f);

    // ---- fallback: CSR aliased Adj -> zero full Adj and scatter dense ----
    if (!csr_in_ws) {
        zero_fill<<<dim3(2048), dim3(256), 0, stream>>>(
            (float4*)Adj, (unsigned int)((size_t)N_NODES * N_NODES / 4));
        adj_scatter<<<dim3(eblocks), dim3(256), 0, stream>>>(tv, ti, deg, Adj);
    }
}

// Round 9
// 1019.889 us; speedup vs baseline: 1.0132x; 1.0132x over previous
//
#include <hip/hip_runtime.h>
#include <hip/hip_bf16.h>
#include <cstddef>

#define N_NODES 10000
#define KTOP 30
#define CAP 2048     // max CSR row length
#define CANDCAP 512
#define NQ4 (N_NODES / 4)   // 2500 float4 per row
#define NTILE 79     // ceil(10000/128)

typedef _Float16 f16x8 __attribute__((ext_vector_type(8)));
typedef float f32x4 __attribute__((ext_vector_type(4)));

// ---------------- fused split pass 1: features rows + W1^T + W2^T ----------------
// split(v): hi = f16(v*256), lo = f16(v*256 - hi); exact 2^8 scale.
__global__ __launch_bounds__(256) void fused_split1(const float* __restrict__ feat,
                                                    _Float16* __restrict__ fhi,
                                                    _Float16* __restrict__ flo,
                                                    const float* __restrict__ W1,
                                                    _Float16* __restrict__ w1hi,
                                                    _Float16* __restrict__ w1lo,
                                                    const float* __restrict__ W2,
                                                    _Float16* __restrict__ w2hi,
                                                    _Float16* __restrict__ w2lo) {
    int b = blockIdx.x;
    int t = threadIdx.x;
    if (b < 10000) {
        int i = b * 256 + t;
        float v = feat[i] * 256.0f;
        _Float16 h = (_Float16)v;
        fhi[i] = h;
        flo[i] = (_Float16)(v - (float)h);
    } else if (b < 10256) {
        int n = b - 10000;
        float v = W1[t * 256 + n] * 256.0f;
        _Float16 h = (_Float16)v;
        w1hi[n * 256 + t] = h;
        w1lo[n * 256 + t] = (_Float16)(v - (float)h);
    } else {
        int n = b - 10256;
        float v = W2[t * 256 + n] * 256.0f;
        _Float16 h = (_Float16)v;
        w2hi[n * 256 + t] = h;
        w2lo[n * 256 + t] = (_Float16)(v - (float)h);
    }
}

// ---------------- fused split pass 2: x rows + Wg1^T (128 cols) ----------------
__global__ __launch_bounds__(256) void fused_split2(const float* __restrict__ x,
                                                    _Float16* __restrict__ xhi,
                                                    _Float16* __restrict__ xlo,
                                                    const float* __restrict__ Wg1,
                                                    _Float16* __restrict__ ghi,
                                                    _Float16* __restrict__ glo) {
    int b = blockIdx.x;
    int t = threadIdx.x;
    if (b < 10000) {
        int i = b * 256 + t;
        float v = x[i] * 256.0f;
        _Float16 h = (_Float16)v;
        xhi[i] = h;
        xlo[i] = (_Float16)(v - (float)h);
    } else {
        int n = b - 10000;
        float v = Wg1[t * 128 + n] * 256.0f;
        _Float16 h = (_Float16)v;
        ghi[n * 256 + t] = h;
        glo[n * 256 + t] = (_Float16)(v - (float)h);
    }
}

// ---------------- row normalize, numpy-pairwise-exact semantics ----------------
__global__ __launch_bounds__(256) void rownorm_np_kernel(const float* __restrict__ h,
                                                         _Float16* __restrict__ hhi,
                                                         _Float16* __restrict__ hlo) {
    __shared__ float row[256];
    __shared__ float denom_sh;
    int r = blockIdx.x;
    int t = threadIdx.x;
    const float* p = h + (size_t)r * 256;
    row[t] = p[t];
    __syncthreads();
    if (t < 16) {
        int half = t >> 3;
        int j = t & 7;
        const float* a = row + half * 128 + j;
        float rr = __fmul_rn(a[0], a[0]);
        #pragma unroll
        for (int i = 1; i < 16; i++) {
            rr = __fadd_rn(rr, __fmul_rn(a[i * 8], a[i * 8]));
        }
        #pragma unroll
        for (int off = 1; off <= 8; off <<= 1) {
            rr = __fadd_rn(rr, __shfl_xor(rr, off, 64));
        }
        if (t == 0) { denom_sh = __fadd_rn(__fsqrt_rn(rr), 1e-8f); }
    }
    __syncthreads();
    float v = __fdiv_rn(row[t], denom_sh);
    float sc = v * 256.0f;                 // exact (power-of-2 scale)
    _Float16 hv = (_Float16)sc;            // RNE to fp16
    float rem = sc - (float)hv;            // exact (Sterbenz-range)
    hhi[(size_t)r * 256 + t] = hv;
    hlo[(size_t)r * 256 + t] = (_Float16)rem;
}

// ---------------- global_load_lds helper ----------------
__device__ __forceinline__ void gload16(const void* g, void* l) {
    __builtin_amdgcn_global_load_lds(
        (const __attribute__((address_space(1))) unsigned int*)g,
        (__attribute__((address_space(3))) unsigned int*)l, 16, 0, 0);
}

// ---------------- S tile GEMM via fp16-split MFMA, double-buffered pipeline ----------------
// Emits per-(row, col-tile) maxes of relu(S) into TM[10000][80]. Mirror writes
// use float4 (4 consecutive rr per (i,j)).
__global__ __launch_bounds__(256) void gemm_s_f16(const _Float16* __restrict__ hi,
                                                  const _Float16* __restrict__ lo,
                                                  float* __restrict__ S,
                                                  float* __restrict__ TM) {
    int rb = blockIdx.y * 128;
    int cb = blockIdx.x * 128;
    if (cb < rb) { return; }
    __shared__ __align__(16) unsigned short Hs[2][16384];  // 2 x 32 KB (A at 0, B at 8192)
    int t = threadIdx.x;
    int w = t >> 6;
    int lane = t & 63;
    int wr = w >> 1, wc = w & 1;          // wave -> 64x64 quadrant
    int lrow = lane & 15, lk = lane >> 4; // mfma A/B fragment mapping
    int lr8 = lane >> 3, ls8 = lane & 7;  // staging: 8 rows x 8 phys slots per 1KB chunk

    int slog = ls8 ^ lr8;                  // logical slot this lane sources
    const char* srcp = (slog < 4) ? (const char*)hi : (const char*)lo;
    int koff = (slog & 3) * 16;            // 16B k-slot within the stage's 64B range
    int cbase = w * 8;

    f32x4 acc[4][4];
    #pragma unroll
    for (int i = 0; i < 4; i++) {
        #pragma unroll
        for (int j = 0; j < 4; j++) {
            f32x4 z = {0.f, 0.f, 0.f, 0.f};
            acc[i][j] = z;
        }
    }

    auto STAGE = [&](int sidx, int b) {
        int kb = sidx * 64;                // byte offset of stage's k-range (32 halves)
        #pragma unroll
        for (int tt = 0; tt < 8; tt++) {
            int c = cbase + tt;            // chunk 0..31
            int rl = ((c & 15) << 3) + lr8;
            int node = ((c >> 4) ? cb : rb) + rl;
            if (node > N_NODES - 1) { node = N_NODES - 1; }
            gload16(srcp + (size_t)node * 512 + kb + koff, &Hs[b][c << 9]);
        }
    };

    STAGE(0, 0);
    #pragma unroll 1
    for (int s = 0; s < 8; s++) {
        int b = s & 1;
        if (s < 7) { STAGE(s + 1, b ^ 1); }
        __builtin_amdgcn_sched_barrier(0);
        if (s < 7) { asm volatile("s_waitcnt vmcnt(8)" ::: "memory"); }
        else       { asm volatile("s_waitcnt vmcnt(0)" ::: "memory"); }
        __builtin_amdgcn_s_barrier();
        __builtin_amdgcn_sched_barrier(0);
        f16x8 ah[4], al[4], bh[4], bl[4];
        #pragma unroll
        for (int i = 0; i < 4; i++) {
            int ar = wr * 64 + i * 16 + lrow;
            int br = wc * 64 + i * 16 + lrow;
            int ra7 = ar & 7, rb7 = br & 7;
            ah[i] = *(const f16x8*)&Hs[b][ar * 64 + ((lk ^ ra7) << 3)];
            al[i] = *(const f16x8*)&Hs[b][ar * 64 + (((lk + 4) ^ ra7) << 3)];
            bh[i] = *(const f16x8*)&Hs[b][8192 + br * 64 + ((lk ^ rb7) << 3)];
            bl[i] = *(const f16x8*)&Hs[b][8192 + br * 64 + (((lk + 4) ^ rb7) << 3)];
        }
        #pragma unroll
        for (int i = 0; i < 4; i++) {
            #pragma unroll
            for (int j = 0; j < 4; j++) {
                acc[i][j] = __builtin_amdgcn_mfma_f32_16x16x32_f16(ah[i], bh[j], acc[i][j], 0, 0, 0);
                acc[i][j] = __builtin_amdgcn_mfma_f32_16x16x32_f16(ah[i], bl[j], acc[i][j], 0, 0, 0);
                acc[i][j] = __builtin_amdgcn_mfma_f32_16x16x32_f16(al[i], bh[j], acc[i][j], 0, 0, 0);
            }
        }
        __builtin_amdgcn_sched_barrier(0);
        __builtin_amdgcn_s_barrier();
    }

    const float inv = 1.0f / 65536.0f;  // undo 2^8 * 2^8 operand scaling (exact)

    // ---- per-(row, tile) maxes: Hs is dead (post trailing barrier) -> scratch.
    {
        float* red = (float*)Hs;       // [0..255] rowpart [wc][128]; [256..511] colpart [wr][128]
        float rm[4][4];
        #pragma unroll
        for (int i = 0; i < 4; i++) {
            #pragma unroll
            for (int q = 0; q < 4; q++) {
                float m = fmaxf(fmaxf(acc[i][0][q], acc[i][1][q]),
                                fmaxf(acc[i][2][q], acc[i][3][q]));
                #pragma unroll
                for (int off = 1; off <= 8; off <<= 1) { m = fmaxf(m, __shfl_xor(m, off, 64)); }
                rm[i][q] = m;
            }
        }
        if ((lane & 15) == 0) {
            #pragma unroll
            for (int i = 0; i < 4; i++) {
                #pragma unroll
                for (int q = 0; q < 4; q++) {
                    red[wc * 128 + wr * 64 + i * 16 + lk * 4 + q] = rm[i][q];
                }
            }
        }
        float cm[4];
        #pragma unroll
        for (int j = 0; j < 4; j++) {
            float m = acc[0][j][0];
            #pragma unroll
            for (int i = 0; i < 4; i++) {
                #pragma unroll
                for (int q = 0; q < 4; q++) {
                    if (i + q) { m = fmaxf(m, acc[i][j][q]); }
                }
            }
            m = fmaxf(m, __shfl_xor(m, 16, 64));
            m = fmaxf(m, __shfl_xor(m, 32, 64));
            cm[j] = m;
        }
        if (lk == 0) {
            #pragma unroll
            for (int j = 0; j < 4; j++) {
                red[256 + wr * 128 + wc * 64 + j * 16 + lrow] = cm[j];
            }
        }
        __syncthreads();
        if (t < 128) {
            float rmx = fmaxf(red[t], red[128 + t]) * inv;
            int gr = rb + t;
            if (gr < N_NODES) { TM[(size_t)gr * 80 + (cb >> 7)] = fmaxf(rmx, 0.f); }
            float cmx = fmaxf(red[256 + t], red[384 + t]) * inv;
            int gc = cb + t;
            if (gc < N_NODES) { TM[(size_t)gc * 80 + (rb >> 7)] = fmaxf(cmx, 0.f); }
        }
    }

    // epilogue: C/D frag layout col = lane&15, row = (lane>>4)*4 + reg.
    #pragma unroll
    for (int i = 0; i < 4; i++) {
        int rrb = rb + wr * 64 + i * 16 + lk * 4;
        #pragma unroll
        for (int j = 0; j < 4; j++) {
            int cc = cb + wc * 64 + j * 16 + lrow;
            if (cc >= N_NODES) { continue; }
            float4 mv;
            float* mp = &mv.x;
            #pragma unroll
            for (int q = 0; q < 4; q++) {
                float v = fmaxf(acc[i][j][q] * inv, 0.f);
                mp[q] = v;
                int rr = rrb + q;
                if (rr < N_NODES) { S[(size_t)rr * N_NODES + cc] = v; }
            }
            if (rrb + 3 < N_NODES) {
                *(float4*)(S + (size_t)cc * N_NODES + rrb) = mv;
            } else {
                #pragma unroll
                for (int q = 0; q < 4; q++) {
                    int rr = rrb + q;
                    if (rr < N_NODES) { S[(size_t)cc * N_NODES + rr] = mp[q]; }
                }
            }
        }
    }
}

// ---------------- generic 128-tile GEMM via fp16-split MFMA ----------------
template<int MODE>
__global__ __launch_bounds__(256) void gemm_mlp(const _Float16* __restrict__ ahi,
                                                const _Float16* __restrict__ alo,
                                                const _Float16* __restrict__ bhi,
                                                const _Float16* __restrict__ blo,
                                                _Float16* __restrict__ chi,
                                                _Float16* __restrict__ clo,
                                                float* __restrict__ cf,
                                                const float* __restrict__ bias,
                                                int on) {
    int rb = blockIdx.y * 128;
    int cb = blockIdx.x * 128;
    __shared__ __align__(16) unsigned short Hs[32768];  // 64 KB
    int t = threadIdx.x;
    int w = t >> 6;
    int lane = t & 63;
    int wr = w >> 1, wc = w & 1;
    int lrow = lane & 15, lk = lane >> 4;
    int lr8 = lane >> 3, ls8 = lane & 7;
    int koffb = ((ls8 ^ lr8) << 4);

    f32x4 acc[4][4];
    #pragma unroll
    for (int i = 0; i < 4; i++) {
        #pragma unroll
        for (int j = 0; j < 4; j++) {
            f32x4 z = {0.f, 0.f, 0.f, 0.f};
            acc[i][j] = z;
        }
    }

    const char* ahp = (const char*)ahi;
    const char* alp = (const char*)alo;
    const char* bhp = (const char*)bhi;
    const char* blp = (const char*)blo;

    #pragma unroll 1
    for (int ks = 0; ks < 4; ks++) {
        int k0b = ks * 128;
        #pragma unroll
        for (int tt = 0; tt < 4; tt++) {
            int c = w * 4 + tt;
            int rowloc = c * 8 + lr8;
            int na = rb + rowloc; if (na > N_NODES - 1) { na = N_NODES - 1; }
            int nb = cb + rowloc;              // Wt rows always valid
            size_t offA = (size_t)na * 512 + k0b + koffb;
            size_t offB = (size_t)nb * 512 + k0b + koffb;
            gload16(ahp + offA, &Hs[0     + c * 512]);
            gload16(alp + offA, &Hs[8192  + c * 512]);
            gload16(bhp + offB, &Hs[16384 + c * 512]);
            gload16(blp + offB, &Hs[24576 + c * 512]);
        }
        __builtin_amdgcn_s_waitcnt(0);
        __syncthreads();
        #pragma unroll 1
        for (int kk = 0; kk < 2; kk++) {
            f16x8 ah[4], al[4], bh[4], bl[4];
            #pragma unroll
            for (int i = 0; i < 4; i++) {
                int ar = wr * 64 + i * 16 + lrow;
                int br = wc * 64 + i * 16 + lrow;
                int ps = ((kk * 4 + lk) ^ (lrow & 7)) * 8;
                ah[i] = *(const f16x8*)&Hs[0     + ar * 64 + ps];
                al[i] = *(const f16x8*)&Hs[8192  + ar * 64 + ps];
                bh[i] = *(const f16x8*)&Hs[16384 + br * 64 + ps];
                bl[i] = *(const f16x8*)&Hs[24576 + br * 64 + ps];
            }
            #pragma unroll
            for (int i = 0; i < 4; i++) {
                #pragma unroll
                for (int j = 0; j < 4; j++) {
                    acc[i][j] = __builtin_amdgcn_mfma_f32_16x16x32_f16(ah[i], bh[j], acc[i][j], 0, 0, 0);
                    acc[i][j] = __builtin_amdgcn_mfma_f32_16x16x32_f16(ah[i], bl[j], acc[i][j], 0, 0, 0);
                    acc[i][j] = __builtin_amdgcn_mfma_f32_16x16x32_f16(al[i], bh[j], acc[i][j], 0, 0, 0);
                }
            }
        }
        __syncthreads();
    }

    const float inv = 1.0f / 65536.0f;
    #pragma unroll
    for (int i = 0; i < 4; i++) {
        int rrb = rb + wr * 64 + i * 16 + lk * 4;
        #pragma unroll
        for (int j = 0; j < 4; j++) {
            int cc = cb + wc * 64 + j * 16 + lrow;
            if (cc >= on && MODE == 0) { continue; }
            #pragma unroll
            for (int q = 0; q < 4; q++) {
                int rr = rrb + q;
                if (rr >= N_NODES) { continue; }
                if (MODE == 1) {
                    float sv = fmaxf(acc[i][j][q], 0.f) * (1.0f / 256.0f);
                    _Float16 hv = (_Float16)sv;
                    chi[(size_t)rr * 256 + cc] = hv;
                    clo[(size_t)rr * 256 + cc] = (_Float16)(sv - (float)hv);
                } else {
                    float v = acc[i][j][q] * inv;
                    if (bias != nullptr) { v += bias[cc]; }
                    cf[(size_t)rr * on + cc] = v;
                }
            }
        }
    }
}

// ---------------- order-statistic-pruned exact top-30, ties -> HIGHEST index ----------------
// 256 threads/row. thr = 30th-largest tile-max (exact superset bound) via rank.
// Collection over 4 waves; selection on wave 0. Fuses degrees (deg pre-zeroed)
// AND the Adj row-zero (stores issued before selection drain in its shadow).
__global__ __launch_bounds__(256) void topk_sel_kernel(float* __restrict__ S,
                                                       const float* __restrict__ TM,
                                                       float* __restrict__ tv,
                                                       int* __restrict__ ti,
                                                       float* __restrict__ deg) {
    __shared__ float cv[CANDCAP];
    __shared__ int ci[CANDCAP];
    __shared__ float tmv[NTILE];
    __shared__ int cntSh;
    __shared__ float thrSh;
    __shared__ float wv[4];
    __shared__ int wi[4];
    int t = threadIdx.x;
    int w = t >> 6;
    int lane = t & 63;
    int r = blockIdx.x;
    float* row = S + (size_t)r * N_NODES;
    const float* trow = TM + (size_t)r * 80;
    if (t == 0) { cntSh = 0; }
    if (t < NTILE) { tmv[t] = trow[t]; }
    __syncthreads();

    // thr by rank: lane ranks its <=2 tile-max values against all 79
    if (t < 64) {
        float v0 = tmv[lane];
        float v1 = (lane + 64 < NTILE) ? tmv[lane + 64] : -3.f;
        int rk0 = 0, rk1 = 0;
        for (int j = 0; j < NTILE; j++) {
            float vj = tmv[j];
            if (vj > v0 || (vj == v0 && j > lane)) { rk0++; }
            if (vj > v1 || (vj == v1 && j > lane + 64)) { rk1++; }
        }
        if (rk0 == KTOP - 1) { thrSh = v0; }
        if (lane + 64 < NTILE && rk1 == KTOP - 1) { thrSh = v1; }
    }
    __syncthreads();
    float thr = thrSh;

    // collection: wave w handles tiles w, w+4, ... (parallel, no insertion)
    for (int tt = w; tt < NTILE; tt += 4) {
        if (tmv[tt] < thr) { continue; }
        int c0 = tt * 128 + lane;
        int c1 = c0 + 64;
        float x0 = (c0 < N_NODES) ? row[c0] : -1.f;
        float x1 = (c1 < N_NODES) ? row[c1] : -1.f;
        if (x0 >= thr) {
            int p = atomicAdd(&cntSh, 1);
            if (p < CANDCAP) { cv[p] = x0; ci[p] = c0; }
        }
        if (x1 >= thr) {
            int p = atomicAdd(&cntSh, 1);
            if (p < CANDCAP) { cv[p] = x1; ci[p] = c1; }
        }
    }
    __syncthreads();
    int ncand = cntSh;
    bool fb = (ncand > CANDCAP) || (ncand < KTOP);

    if (fb) {
        // exact fallback over the intact row (value desc, index desc), 256t
        float rs = 0.f;
        for (int k = 0; k < KTOP; k++) {
            float bv = -1.f;
            int bi = -1;
            for (int j = t; j < N_NODES; j += 256) {
                float v = row[j];
                if (v >= bv) { bv = v; bi = j; }
            }
            #pragma unroll
            for (int off = 32; off > 0; off >>= 1) {
                float ov = __shfl_down(bv, off, 64);
                int oi = __shfl_down(bi, off, 64);
                if (ov > bv || (ov == bv && oi > bi)) { bv = ov; bi = oi; }
            }
            if (lane == 0) { wv[w] = bv; wi[w] = bi; }
            __syncthreads();
            if (t == 0) {
                float fv = wv[0];
                int fi = wi[0];
                for (int q = 1; q < 4; q++) {
                    if (wv[q] > fv || (wv[q] == fv && wi[q] > fi)) { fv = wv[q]; fi = wi[q]; }
                }
                tv[r * KTOP + k] = fv;
                ti[r * KTOP + k] = fi;
                atomicAdd(deg + fi, 0.5f * fv);
                rs += fv;
                row[fi] = -1.f;
            }
            __syncthreads();
        }
        if (t == 0) { atomicAdd(deg + r, 0.5f * rs); }
        // zero row after fallback selection (fused Adj-zero)
        float4 z = {0.f, 0.f, 0.f, 0.f};
        for (int u = t; u < NQ4; u += 256) { *(float4*)(row + 4 * u) = z; }
        return;
    }

    // fused Adj-zero: wipe own row with all 256 threads (drains under selection)
    {
        float4 z = {0.f, 0.f, 0.f, 0.f};
        for (int u = t; u < NQ4; u += 256) { *(float4*)(row + 4 * u) = z; }
    }

    // selection: wave 0 only, barrier-free (intra-wave LDS is program-ordered)
    if (t < 64) {
        float rs = 0.f;
        if (ncand <= 128) {
            float v0 = -2.f, v1 = -2.f;
            int i0 = -1, i1 = -1;
            if (lane < ncand) { v0 = cv[lane]; i0 = ci[lane]; }
            if (lane + 64 < ncand) { v1 = cv[lane + 64]; i1 = ci[lane + 64]; }
            for (int k = 0; k < KTOP; k++) {
                bool sel1 = (v1 > v0) || (v1 == v0 && i1 > i0);
                float bv = sel1 ? v1 : v0;
                int bi = sel1 ? i1 : i0;
                #pragma unroll
                for (int m = 32; m > 0; m >>= 1) {
                    float ov = __shfl_xor(bv, m, 64);
                    int oi = __shfl_xor(bi, m, 64);
                    if (ov > bv || (ov == bv && oi > bi)) { bv = ov; bi = oi; }
                }
                if (lane == 0) {
                    tv[r * KTOP + k] = bv;
                    ti[r * KTOP + k] = bi;
                    atomicAdd(deg + bi, 0.5f * bv);
                    rs += bv;
                }
                if (i0 == bi) { v0 = -2.f; }
                if (i1 == bi) { v1 = -2.f; }
            }
        } else {
            for (int k = 0; k < KTOP; k++) {
                float bv = -2.f;
                int bi = -1;
                int bq = -1;
                for (int q = lane; q < ncand; q += 64) {
                    float v = cv[q];
                    int idx = ci[q];
                    if (v > bv || (v == bv && idx > bi)) { bv = v; bi = idx; bq = q; }
                }
                #pragma unroll
                for (int m = 32; m > 0; m >>= 1) {
                    float ov = __shfl_xor(bv, m, 64);
                    int oi = __shfl_xor(bi, m, 64);
                    int oq = __shfl_xor(bq, m, 64);
                    if (ov > bv || (ov == bv && oi > bi)) { bv = ov; bi = oi; bq = oq; }
                }
                if (lane == 0) {
                    tv[r * KTOP + k] = bv;
                    ti[r * KTOP + k] = bi;
                    atomicAdd(deg + bi, 0.5f * bv);
                    rs += bv;
                    cv[bq] = -2.f;
                }
            }
        }
        if (lane == 0) { atomicAdd(deg + r, 0.5f * rs); }
    }
}

// ---------------- zero fill (fallback path only: CSR aliases Adj) ----------------
__global__ __launch_bounds__(256) void zero_fill(float4* __restrict__ p, unsigned int n4) {
    unsigned int i = blockIdx.x * 256u + threadIdx.x;
    unsigned int stride = gridDim.x * 256u;
    float4 z = {0.f, 0.f, 0.f, 0.f};
    for (; i < n4; i += stride) { p[i] = z; }
}

// ---------------- CSR build (+ optional fused dense Adj scatter); dis inlined ----------------
template<int WRITE_ADJ>
__global__ __launch_bounds__(256) void csr_adj(const float* __restrict__ tv,
                                               const int* __restrict__ ti,
                                               const float* __restrict__ deg,
                                               int* __restrict__ cnt,
                                               int* __restrict__ nbr,
                                               float* __restrict__ wgt,
                                               float* __restrict__ Adj) {
    int e = blockIdx.x * 256 + threadIdx.x;
    if (e >= N_NODES * KTOP) { return; }
    int i = e / KTOP;
    int j = ti[e];
    float v = tv[e];
    float vrev = 0.f;
    bool mutual = false;
    const int* tj = ti + (size_t)j * KTOP;
    const float* tvj = tv + (size_t)j * KTOP;
    for (int k = 0; k < KTOP; k++) {
        if (tj[k] == i) { vrev = tvj[k]; mutual = true; }
    }
    float dgi = deg[i];
    float dgj = deg[j];
    float di = dgi > 0.f ? 1.f / sqrtf(fmaxf(dgi, 1e-8f)) : 0.f;
    float dj = dgj > 0.f ? 1.f / sqrtf(fmaxf(dgj, 1e-8f)) : 0.f;
    float w = 0.5f * (v + vrev) * di * dj;
    int p = atomicAdd(cnt + i, 1);
    if (p < CAP) {
        nbr[(size_t)i * CAP + p] = j;
        wgt[(size_t)i * CAP + p] = w;
    }
    if (!mutual) {
        int p2 = atomicAdd(cnt + j, 1);
        if (p2 < CAP) {
            nbr[(size_t)j * CAP + p2] = i;
            wgt[(size_t)j * CAP + p2] = w;
        }
    }
    if (WRITE_ADJ) {
        Adj[(size_t)i * N_NODES + j] = w;
        Adj[(size_t)j * N_NODES + i] = w;
    }
}

// ---------------- Adj scatter (fallback path only); dis inlined ----------------
__global__ __launch_bounds__(256) void adj_scatter(const float* __restrict__ tv,
                                                   const int* __restrict__ ti,
                                                   const float* __restrict__ deg,
                                                   float* __restrict__ Adj) {
    int e = blockIdx.x * 256 + threadIdx.x;
    if (e >= N_NODES * KTOP) { return; }
    int i = e / KTOP;
    int j = ti[e];
    float v = tv[e];
    float vrev = 0.f;
    const int* tj = ti + (size_t)j * KTOP;
    const float* tvj = tv + (size_t)j * KTOP;
    for (int k = 0; k < KTOP; k++) {
        if (tj[k] == i) { vrev = tvj[k]; }
    }
    float dgi = deg[i];
    float dgj = deg[j];
    float di = dgi > 0.f ? 1.f / sqrtf(fmaxf(dgi, 1e-8f)) : 0.f;
    float dj = dgj > 0.f ? 1.f / sqrtf(fmaxf(dgj, 1e-8f)) : 0.f;
    float w = 0.5f * (v + vrev) * di * dj;
    Adj[(size_t)i * N_NODES + j] = w;
    Adj[(size_t)j * N_NODES + i] = w;
}

// ---------------- gather SpMM, 128 channels, relu fused (4x ILP) ----------------
__global__ __launch_bounds__(256) void gather128(const int* __restrict__ cnt,
                                                 const int* __restrict__ nbr,
                                                 const float* __restrict__ wgt,
                                                 const float* __restrict__ T,
                                                 float* __restrict__ Y) {
    int node = blockIdx.x * 2 + (threadIdx.x >> 7);
    int c = threadIdx.x & 127;
    if (node >= N_NODES) { return; }
    int n = cnt[node];
    if (n > CAP) { n = CAP; }
    const int* nb = nbr + (size_t)node * CAP;
    const float* wg = wgt + (size_t)node * CAP;
    float a0 = 0.f, a1 = 0.f, a2 = 0.f, a3 = 0.f;
    int k = 0;
    for (; k + 4 <= n; k += 4) {
        int4 j = *(const int4*)(nb + k);
        float4 w = *(const float4*)(wg + k);
        float t0 = T[(size_t)j.x * 128 + c];
        float t1 = T[(size_t)j.y * 128 + c];
        float t2 = T[(size_t)j.z * 128 + c];
        float t3 = T[(size_t)j.w * 128 + c];
        a0 = fmaf(w.x, t0, a0);
        a1 = fmaf(w.y, t1, a1);
        a2 = fmaf(w.z, t2, a2);
        a3 = fmaf(w.w, t3, a3);
    }
    for (; k < n; k++) { a0 = fmaf(wg[k], T[(size_t)nb[k] * 128 + c], a0); }
    float acc = (a0 + a1) + (a2 + a3);
    Y[(size_t)node * 128 + c] = fmaxf(acc, 0.f);
}

// ---------------- y1[M,128] @ Wg2[128,16] + bg2 -> t2[M,16] ----------------
__global__ __launch_bounds__(256) void gemm16(const float* __restrict__ y1,
                                              const float* __restrict__ Wg2,
                                              const float* __restrict__ bg2,
                                              float* __restrict__ out) {
    __shared__ float Ws[2048];
    __shared__ float Ys[16 * 132];
    int t = threadIdx.x;
    int n0 = blockIdx.x * 16;
    for (int i = t; i < 2048; i += 256) {
        Ws[i] = Wg2[i];
        int rr = i >> 7, cc = i & 127;
        int node = n0 + rr;
        if (node > N_NODES - 1) { node = N_NODES - 1; }
        Ys[rr * 132 + cc] = y1[(size_t)node * 128 + cc];
    }
    __syncthreads();
    int nn = t >> 4;
    int c = t & 15;
    int node = n0 + nn;
    if (node >= N_NODES) { return; }
    const float* yr = Ys + nn * 132;
    float acc = 0.f;
    #pragma unroll 4
    for (int k = 0; k < 128; k++) {
        acc = fmaf(yr[k], Ws[k * 16 + c], acc);
    }
    out[(size_t)node * 16 + c] = acc + bg2[c];
}

// ---------------- gather SpMM, 16 channels (4x ILP) ----------------
__global__ __launch_bounds__(256) void gather16(const int* __restrict__ cnt,
                                                const int* __restrict__ nbr,
                                                const float* __restrict__ wgt,
                                                const float* __restrict__ T,
                                                float* __restrict__ Y) {
    int node = blockIdx.x * 16 + (threadIdx.x >> 4);
    int c = threadIdx.x & 15;
    if (node >= N_NODES) { return; }
    int n = cnt[node];
    if (n > CAP) { n = CAP; }
    const int* nb = nbr + (size_t)node * CAP;
    const float* wg = wgt + (size_t)node * CAP;
    float a0 = 0.f, a1 = 0.f, a2 = 0.f, a3 = 0.f;
    int k = 0;
    for (; k + 4 <= n; k += 4) {
        int4 j = *(const int4*)(nb + k);
        float4 w = *(const float4*)(wg + k);
        float t0 = T[(size_t)j.x * 16 + c];
        float t1 = T[(size_t)j.y * 16 + c];
        float t2 = T[(size_t)j.z * 16 + c];
        float t3 = T[(size_t)j.w * 16 + c];
        a0 = fmaf(w.x, t0, a0);
        a1 = fmaf(w.y, t1, a1);
        a2 = fmaf(w.z, t2, a2);
        a3 = fmaf(w.w, t3, a3);
    }
    for (; k < n; k++) { a0 = fmaf(wg[k], T[(size_t)nb[k] * 16 + c], a0); }
    Y[(size_t)node * 16 + c] = (a0 + a1) + (a2 + a3);
}

extern "C" void kernel_launch(void* const* d_in, const int* in_sizes, int n_in,
                              void* d_out, int out_size, void* d_ws, size_t ws_size,
                              hipStream_t stream) {
    const float* features = (const float*)d_in[0];
    const float* x   = (const float*)d_in[1];
    const float* W1  = (const float*)d_in[2];
    const float* W2  = (const float*)d_in[3];
    const float* Wg1 = (const float*)d_in[4];
    const float* bg1 = (const float*)d_in[5];
    const float* Wg2 = (const float*)d_in[6];
    const float* bg2 = (const float*)d_in[7];

    float* ws = (float*)d_ws;
    // region A [0, 2.56M) floats: fsp -> hbuf -> tmax -> xsp
    // region B [2.56M, 5.12M) floats: h1sp -> Hhi/Hlo -> t1 | y1
    float* hbuf = ws;
    float* tmax = ws;                          // 800,000 f (10000 x 80), over dead hbuf
    float* tv   = ws + 5120000;               // 300,000 f
    int*   ti   = (int*)(ws + 5420000);       // 300,000 i
    float* deg  = ws + 5720000;               // 10,000 f
    int*   cnt  = (int*)(ws + 5730000);       // 10,000 i (adjacent to deg: one memset)
    float* t2   = ws + 5740000;               // 160,000 f (W-splits live here early)
    float* t1   = ws + 2560000;               // Hhi region, after gemm_s dead
    float* y1   = ws + 3840000;               // Hlo region, after gemm_s dead

    _Float16* fsphi = (_Float16*)ws;
    _Float16* fsplo = fsphi + 2560000;
    _Float16* xsphi = (_Float16*)ws;                    // after tmax dead (post topk)
    _Float16* xsplo = xsphi + 2560000;
    _Float16* h1hi = (_Float16*)(ws + 2560000);
    _Float16* h1lo = h1hi + 2560000;
    _Float16* Hhi  = (_Float16*)(ws + 2560000);
    _Float16* Hlo  = Hhi + 2560000;
    _Float16* W1thi = (_Float16*)(ws + 5740000);        // 65,536 halves each
    _Float16* W1tlo = W1thi + 65536;
    _Float16* W2thi = W1thi + 131072;
    _Float16* W2tlo = W1thi + 196608;
    _Float16* Wg1thi = (_Float16*)(ws + 5740000);       // reuse after MLP chain (128x256)
    _Float16* Wg1tlo = Wg1thi + 32768;

    float* out_f = (float*)d_out;             // 160,000 f32
    float* Adj   = out_f + 160000;            // 1e8 f32 = 400 MB
    float* Sbuf  = Adj;                       // S until topk (topk zeroes it)

    // CSR placement: workspace if it fits, else alias Adj (zero+scatter at end)
    size_t csr_off = 5910000;                                  // floats
    size_t csr_need = (csr_off + (size_t)N_NODES * CAP * 2) * sizeof(float);
    bool csr_in_ws = ws_size >= csr_need;
    int*   nbr = csr_in_ws ? (int*)(ws + csr_off) : (int*)Adj;
    float* wgt = csr_in_ws ? (float*)(ws + csr_off + (size_t)N_NODES * CAP)
                           : (float*)(Adj + (size_t)N_NODES * CAP);

    // ---- splits (one launch) + MLP chain via fp16-split MFMA ----
    fused_split1<<<dim3(10512), dim3(256), 0, stream>>>(
        features, fsphi, fsplo, W1, W1thi, W1tlo, W2, W2thi, W2tlo);
    gemm_mlp<1><<<dim3(2, 79), dim3(256), 0, stream>>>(
        fsphi, fsplo, W1thi, W1tlo, h1hi, h1lo, (float*)nullptr, (const float*)nullptr, 256);
    gemm_mlp<0><<<dim3(2, 79), dim3(256), 0, stream>>>(
        h1hi, h1lo, W2thi, W2tlo, (_Float16*)nullptr, (_Float16*)nullptr, hbuf,
        (const float*)nullptr, 256);
    rownorm_np_kernel<<<dim3(N_NODES), dim3(256), 0, stream>>>(hbuf, Hhi, Hlo);

    // ---- S (triangle + mirror) + tile maxes; pruned exact top-30 + zero + degrees ----
    gemm_s_f16<<<dim3(79, 79), dim3(256), 0, stream>>>(Hhi, Hlo, Sbuf, tmax);
    hipMemsetAsync(deg, 0, 2 * N_NODES * sizeof(float), stream);   // deg + cnt
    topk_sel_kernel<<<dim3(N_NODES), dim3(256), 0, stream>>>(Sbuf, tmax, tv, ti, deg);

    // ---- x + Wg1 splits (one launch; tmax + W1t/W2t dead) + GCN layer-1 GEMM ----
    fused_split2<<<dim3(10128), dim3(256), 0, stream>>>(
        x, xsphi, xsplo, Wg1, Wg1thi, Wg1tlo);
    gemm_mlp<0><<<dim3(1, 79), dim3(256), 0, stream>>>(
        xsphi, xsplo, Wg1thi, Wg1tlo, (_Float16*)nullptr, (_Float16*)nullptr, t1, bg1, 128);

    // ---- CSR build (+ fused Adj scatter when CSR lives in ws; S zeroed by topk) ----
    int eblocks = (N_NODES * KTOP + 255) / 256;
    if (csr_in_ws) {
        csr_adj<1><<<dim3(eblocks), dim3(256), 0, stream>>>(tv, ti, deg, cnt, nbr, wgt, Adj);
    } else {
        csr_adj<0><<<dim3(eblocks), dim3(256), 0, stream>>>(tv, ti, deg, cnt, nbr, wgt, Adj);
    }

    // ---- GCN layers via gather SpMM ----
    gather128<<<dim3(N_NODES / 2), dim3(256), 0, stream>>>(cnt, nbr, wgt, t1, y1);
    gemm16<<<dim3(625), dim3(256), 0, stream>>>(y1, Wg2, bg2, t2);
    gather16<<<dim3((N_NODES + 15) / 16), dim3(256), 0, stream>>>(cnt, nbr, wgt, t2, out_f);

    // ---- fallback: CSR aliased Adj -> zero full Adj and scatter dense ----
    if (!csr_in_ws) {
        zero_fill<<<dim3(2048), dim3(256), 0, stream>>>(
            (float4*)Adj, (unsigned int)((size_t)N_NODES * N_NODES / 4));
        adj_scatter<<<dim3(eblocks), dim3(256), 0, stream>>>(tv, ti, deg, Adj);
    }
}

// Round 10
// 979.412 us; speedup vs baseline: 1.0551x; 1.0413x over previous
//
#include <hip/hip_runtime.h>
#include <hip/hip_bf16.h>
#include <cstddef>

#define N_NODES 10000
#define KTOP 30
#define CAP 2048     // max CSR row length
#define CANDCAP 512
#define NQ4 (N_NODES / 4)   // 2500 float4 per row
#define NTILE 79     // ceil(10000/128)
#define NTRI (NTILE * (NTILE + 1) / 2)   // 3160 upper-triangle tile pairs

typedef _Float16 f16x8 __attribute__((ext_vector_type(8)));
typedef float f32x4 __attribute__((ext_vector_type(4)));

// ---------------- fused split pass 1: features rows + W1^T + W2^T ----------------
// split(v): hi = f16(v*256), lo = f16(v*256 - hi); exact 2^8 scale.
__global__ __launch_bounds__(256) void fused_split1(const float* __restrict__ feat,
                                                    _Float16* __restrict__ fhi,
                                                    _Float16* __restrict__ flo,
                                                    const float* __restrict__ W1,
                                                    _Float16* __restrict__ w1hi,
                                                    _Float16* __restrict__ w1lo,
                                                    const float* __restrict__ W2,
                                                    _Float16* __restrict__ w2hi,
                                                    _Float16* __restrict__ w2lo) {
    int b = blockIdx.x;
    int t = threadIdx.x;
    if (b < 10000) {
        int i = b * 256 + t;
        float v = feat[i] * 256.0f;
        _Float16 h = (_Float16)v;
        fhi[i] = h;
        flo[i] = (_Float16)(v - (float)h);
    } else if (b < 10256) {
        int n = b - 10000;
        float v = W1[t * 256 + n] * 256.0f;
        _Float16 h = (_Float16)v;
        w1hi[n * 256 + t] = h;
        w1lo[n * 256 + t] = (_Float16)(v - (float)h);
    } else {
        int n = b - 10256;
        float v = W2[t * 256 + n] * 256.0f;
        _Float16 h = (_Float16)v;
        w2hi[n * 256 + t] = h;
        w2lo[n * 256 + t] = (_Float16)(v - (float)h);
    }
}

// ---------------- fused split pass 2: x rows + Wg1^T (128 cols) ----------------
__global__ __launch_bounds__(256) void fused_split2(const float* __restrict__ x,
                                                    _Float16* __restrict__ xhi,
                                                    _Float16* __restrict__ xlo,
                                                    const float* __restrict__ Wg1,
                                                    _Float16* __restrict__ ghi,
                                                    _Float16* __restrict__ glo) {
    int b = blockIdx.x;
    int t = threadIdx.x;
    if (b < 10000) {
        int i = b * 256 + t;
        float v = x[i] * 256.0f;
        _Float16 h = (_Float16)v;
        xhi[i] = h;
        xlo[i] = (_Float16)(v - (float)h);
    } else {
        int n = b - 10000;
        float v = Wg1[t * 128 + n] * 256.0f;
        _Float16 h = (_Float16)v;
        ghi[n * 256 + t] = h;
        glo[n * 256 + t] = (_Float16)(v - (float)h);
    }
}

// ---------------- row normalize, numpy-pairwise-exact semantics ----------------
// Also zeroes deg[r]/cnt[r] (consumed only by topk/csr_adj, both later).
__global__ __launch_bounds__(256) void rownorm_np_kernel(const float* __restrict__ h,
                                                         _Float16* __restrict__ hhi,
                                                         _Float16* __restrict__ hlo,
                                                         float* __restrict__ deg,
                                                         int* __restrict__ cnt) {
    __shared__ float row[256];
    __shared__ float denom_sh;
    int r = blockIdx.x;
    int t = threadIdx.x;
    const float* p = h + (size_t)r * 256;
    row[t] = p[t];
    if (t == 0) { deg[r] = 0.f; cnt[r] = 0; }
    __syncthreads();
    if (t < 16) {
        int half = t >> 3;
        int j = t & 7;
        const float* a = row + half * 128 + j;
        float rr = __fmul_rn(a[0], a[0]);
        #pragma unroll
        for (int i = 1; i < 16; i++) {
            rr = __fadd_rn(rr, __fmul_rn(a[i * 8], a[i * 8]));
        }
        #pragma unroll
        for (int off = 1; off <= 8; off <<= 1) {
            rr = __fadd_rn(rr, __shfl_xor(rr, off, 64));
        }
        if (t == 0) { denom_sh = __fadd_rn(__fsqrt_rn(rr), 1e-8f); }
    }
    __syncthreads();
    float v = __fdiv_rn(row[t], denom_sh);
    float sc = v * 256.0f;                 // exact (power-of-2 scale)
    _Float16 hv = (_Float16)sc;            // RNE to fp16
    float rem = sc - (float)hv;            // exact (Sterbenz-range)
    hhi[(size_t)r * 256 + t] = hv;
    hlo[(size_t)r * 256 + t] = (_Float16)rem;
}

// ---------------- global_load_lds helper ----------------
__device__ __forceinline__ void gload16(const void* g, void* l) {
    __builtin_amdgcn_global_load_lds(
        (const __attribute__((address_space(1))) unsigned int*)g,
        (__attribute__((address_space(3))) unsigned int*)l, 16, 0, 0);
}

// ---------------- S tile GEMM via fp16-split MFMA, double-buffered pipeline ----------------
// 1-D triangular grid (no dead blocks). Emits per-(row, col-tile) maxes into
// TM[10000][80]. S stores are NONTEMPORAL (write-once 390 MB; keeps L3 for
// hn/TM/T reuse — topk re-reads only ~8% of S).
__global__ __launch_bounds__(256) void gemm_s_f16(const _Float16* __restrict__ hi,
                                                  const _Float16* __restrict__ lo,
                                                  float* __restrict__ S,
                                                  float* __restrict__ TM) {
    // decode linear triangle index -> (i <= j) tile pair
    int bidx = blockIdx.x;
    int ti_ = (int)(79.5f - sqrtf(79.5f * 79.5f - 2.0f * (float)bidx));
    if (ti_ < 0) { ti_ = 0; }
    // off(i) = i*NTILE - i*(i-1)/2
    while (ti_ + 1 <= NTILE - 1 &&
           (ti_ + 1) * NTILE - ((ti_ + 1) * ti_) / 2 <= bidx) { ti_++; }
    while (ti_ * NTILE - (ti_ * (ti_ - 1)) / 2 > bidx) { ti_--; }
    int tj_ = ti_ + (bidx - (ti_ * NTILE - (ti_ * (ti_ - 1)) / 2));
    int rb = ti_ * 128;
    int cb = tj_ * 128;

    __shared__ __align__(16) unsigned short Hs[2][16384];  // 2 x 32 KB (A at 0, B at 8192)
    int t = threadIdx.x;
    int w = t >> 6;
    int lane = t & 63;
    int wr = w >> 1, wc = w & 1;          // wave -> 64x64 quadrant
    int lrow = lane & 15, lk = lane >> 4; // mfma A/B fragment mapping
    int lr8 = lane >> 3, ls8 = lane & 7;  // staging: 8 rows x 8 phys slots per 1KB chunk

    int slog = ls8 ^ lr8;                  // logical slot this lane sources
    const char* srcp = (slog < 4) ? (const char*)hi : (const char*)lo;
    int koff = (slog & 3) * 16;            // 16B k-slot within the stage's 64B range
    int cbase = w * 8;

    f32x4 acc[4][4];
    #pragma unroll
    for (int i = 0; i < 4; i++) {
        #pragma unroll
        for (int j = 0; j < 4; j++) {
            f32x4 z = {0.f, 0.f, 0.f, 0.f};
            acc[i][j] = z;
        }
    }

    auto STAGE = [&](int sidx, int b) {
        int kb = sidx * 64;                // byte offset of stage's k-range (32 halves)
        #pragma unroll
        for (int tt = 0; tt < 8; tt++) {
            int c = cbase + tt;            // chunk 0..31
            int rl = ((c & 15) << 3) + lr8;
            int node = ((c >> 4) ? cb : rb) + rl;
            if (node > N_NODES - 1) { node = N_NODES - 1; }
            gload16(srcp + (size_t)node * 512 + kb + koff, &Hs[b][c << 9]);
        }
    };

    STAGE(0, 0);
    #pragma unroll 1
    for (int s = 0; s < 8; s++) {
        int b = s & 1;
        if (s < 7) { STAGE(s + 1, b ^ 1); }
        __builtin_amdgcn_sched_barrier(0);
        if (s < 7) { asm volatile("s_waitcnt vmcnt(8)" ::: "memory"); }
        else       { asm volatile("s_waitcnt vmcnt(0)" ::: "memory"); }
        __builtin_amdgcn_s_barrier();
        __builtin_amdgcn_sched_barrier(0);
        f16x8 ah[4], al[4], bh[4], bl[4];
        #pragma unroll
        for (int i = 0; i < 4; i++) {
            int ar = wr * 64 + i * 16 + lrow;
            int br = wc * 64 + i * 16 + lrow;
            int ra7 = ar & 7, rb7 = br & 7;
            ah[i] = *(const f16x8*)&Hs[b][ar * 64 + ((lk ^ ra7) << 3)];
            al[i] = *(const f16x8*)&Hs[b][ar * 64 + (((lk + 4) ^ ra7) << 3)];
            bh[i] = *(const f16x8*)&Hs[b][8192 + br * 64 + ((lk ^ rb7) << 3)];
            bl[i] = *(const f16x8*)&Hs[b][8192 + br * 64 + (((lk + 4) ^ rb7) << 3)];
        }
        #pragma unroll
        for (int i = 0; i < 4; i++) {
            #pragma unroll
            for (int j = 0; j < 4; j++) {
                acc[i][j] = __builtin_amdgcn_mfma_f32_16x16x32_f16(ah[i], bh[j], acc[i][j], 0, 0, 0);
                acc[i][j] = __builtin_amdgcn_mfma_f32_16x16x32_f16(ah[i], bl[j], acc[i][j], 0, 0, 0);
                acc[i][j] = __builtin_amdgcn_mfma_f32_16x16x32_f16(al[i], bh[j], acc[i][j], 0, 0, 0);
            }
        }
        __builtin_amdgcn_sched_barrier(0);
        __builtin_amdgcn_s_barrier();
    }

    const float inv = 1.0f / 65536.0f;  // undo 2^8 * 2^8 operand scaling (exact)

    // ---- per-(row, tile) maxes: Hs is dead (post trailing barrier) -> scratch.
    {
        float* red = (float*)Hs;       // [0..255] rowpart [wc][128]; [256..511] colpart [wr][128]
        float rm[4][4];
        #pragma unroll
        for (int i = 0; i < 4; i++) {
            #pragma unroll
            for (int q = 0; q < 4; q++) {
                float m = fmaxf(fmaxf(acc[i][0][q], acc[i][1][q]),
                                fmaxf(acc[i][2][q], acc[i][3][q]));
                #pragma unroll
                for (int off = 1; off <= 8; off <<= 1) { m = fmaxf(m, __shfl_xor(m, off, 64)); }
                rm[i][q] = m;
            }
        }
        if ((lane & 15) == 0) {
            #pragma unroll
            for (int i = 0; i < 4; i++) {
                #pragma unroll
                for (int q = 0; q < 4; q++) {
                    red[wc * 128 + wr * 64 + i * 16 + lk * 4 + q] = rm[i][q];
                }
            }
        }
        float cm[4];
        #pragma unroll
        for (int j = 0; j < 4; j++) {
            float m = acc[0][j][0];
            #pragma unroll
            for (int i = 0; i < 4; i++) {
                #pragma unroll
                for (int q = 0; q < 4; q++) {
                    if (i + q) { m = fmaxf(m, acc[i][j][q]); }
                }
            }
            m = fmaxf(m, __shfl_xor(m, 16, 64));
            m = fmaxf(m, __shfl_xor(m, 32, 64));
            cm[j] = m;
        }
        if (lk == 0) {
            #pragma unroll
            for (int j = 0; j < 4; j++) {
                red[256 + wr * 128 + wc * 64 + j * 16 + lrow] = cm[j];
            }
        }
        __syncthreads();
        if (t < 128) {
            float rmx = fmaxf(red[t], red[128 + t]) * inv;
            int gr = rb + t;
            if (gr < N_NODES) { TM[(size_t)gr * 80 + (cb >> 7)] = fmaxf(rmx, 0.f); }
            float cmx = fmaxf(red[256 + t], red[384 + t]) * inv;
            int gc = cb + t;
            if (gc < N_NODES) { TM[(size_t)gc * 80 + (rb >> 7)] = fmaxf(cmx, 0.f); }
        }
    }

    // epilogue: C/D frag layout col = lane&15, row = (lane>>4)*4 + reg.
    // S stores nontemporal (write-once; avoid L3 thrash).
    #pragma unroll
    for (int i = 0; i < 4; i++) {
        int rrb = rb + wr * 64 + i * 16 + lk * 4;
        #pragma unroll
        for (int j = 0; j < 4; j++) {
            int cc = cb + wc * 64 + j * 16 + lrow;
            if (cc >= N_NODES) { continue; }
            f32x4 mv;
            #pragma unroll
            for (int q = 0; q < 4; q++) {
                float v = fmaxf(acc[i][j][q] * inv, 0.f);
                mv[q] = v;
                int rr = rrb + q;
                if (rr < N_NODES) {
                    __builtin_nontemporal_store(v, S + (size_t)rr * N_NODES + cc);
                }
            }
            if (rrb + 3 < N_NODES) {
                __builtin_nontemporal_store(mv, (f32x4*)(S + (size_t)cc * N_NODES + rrb));
            } else {
                #pragma unroll
                for (int q = 0; q < 4; q++) {
                    int rr = rrb + q;
                    if (rr < N_NODES) {
                        __builtin_nontemporal_store(mv[q], S + (size_t)cc * N_NODES + rr);
                    }
                }
            }
        }
    }
}

// ---------------- generic 128-tile GEMM via fp16-split MFMA ----------------
template<int MODE>
__global__ __launch_bounds__(256) void gemm_mlp(const _Float16* __restrict__ ahi,
                                                const _Float16* __restrict__ alo,
                                                const _Float16* __restrict__ bhi,
                                                const _Float16* __restrict__ blo,
                                                _Float16* __restrict__ chi,
                                                _Float16* __restrict__ clo,
                                                float* __restrict__ cf,
                                                const float* __restrict__ bias,
                                                int on) {
    int rb = blockIdx.y * 128;
    int cb = blockIdx.x * 128;
    __shared__ __align__(16) unsigned short Hs[32768];  // 64 KB
    int t = threadIdx.x;
    int w = t >> 6;
    int lane = t & 63;
    int wr = w >> 1, wc = w & 1;
    int lrow = lane & 15, lk = lane >> 4;
    int lr8 = lane >> 3, ls8 = lane & 7;
    int koffb = ((ls8 ^ lr8) << 4);

    f32x4 acc[4][4];
    #pragma unroll
    for (int i = 0; i < 4; i++) {
        #pragma unroll
        for (int j = 0; j < 4; j++) {
            f32x4 z = {0.f, 0.f, 0.f, 0.f};
            acc[i][j] = z;
        }
    }

    const char* ahp = (const char*)ahi;
    const char* alp = (const char*)alo;
    const char* bhp = (const char*)bhi;
    const char* blp = (const char*)blo;

    #pragma unroll 1
    for (int ks = 0; ks < 4; ks++) {
        int k0b = ks * 128;
        #pragma unroll
        for (int tt = 0; tt < 4; tt++) {
            int c = w * 4 + tt;
            int rowloc = c * 8 + lr8;
            int na = rb + rowloc; if (na > N_NODES - 1) { na = N_NODES - 1; }
            int nb = cb + rowloc;              // Wt rows always valid
            size_t offA = (size_t)na * 512 + k0b + koffb;
            size_t offB = (size_t)nb * 512 + k0b + koffb;
            gload16(ahp + offA, &Hs[0     + c * 512]);
            gload16(alp + offA, &Hs[8192  + c * 512]);
            gload16(bhp + offB, &Hs[16384 + c * 512]);
            gload16(blp + offB, &Hs[24576 + c * 512]);
        }
        __builtin_amdgcn_s_waitcnt(0);
        __syncthreads();
        #pragma unroll 1
        for (int kk = 0; kk < 2; kk++) {
            f16x8 ah[4], al[4], bh[4], bl[4];
            #pragma unroll
            for (int i = 0; i < 4; i++) {
                int ar = wr * 64 + i * 16 + lrow;
                int br = wc * 64 + i * 16 + lrow;
                int ps = ((kk * 4 + lk) ^ (lrow & 7)) * 8;
                ah[i] = *(const f16x8*)&Hs[0     + ar * 64 + ps];
                al[i] = *(const f16x8*)&Hs[8192  + ar * 64 + ps];
                bh[i] = *(const f16x8*)&Hs[16384 + br * 64 + ps];
                bl[i] = *(const f16x8*)&Hs[24576 + br * 64 + ps];
            }
            #pragma unroll
            for (int i = 0; i < 4; i++) {
                #pragma unroll
                for (int j = 0; j < 4; j++) {
                    acc[i][j] = __builtin_amdgcn_mfma_f32_16x16x32_f16(ah[i], bh[j], acc[i][j], 0, 0, 0);
                    acc[i][j] = __builtin_amdgcn_mfma_f32_16x16x32_f16(ah[i], bl[j], acc[i][j], 0, 0, 0);
                    acc[i][j] = __builtin_amdgcn_mfma_f32_16x16x32_f16(al[i], bh[j], acc[i][j], 0, 0, 0);
                }
            }
        }
        __syncthreads();
    }

    const float inv = 1.0f / 65536.0f;
    #pragma unroll
    for (int i = 0; i < 4; i++) {
        int rrb = rb + wr * 64 + i * 16 + lk * 4;
        #pragma unroll
        for (int j = 0; j < 4; j++) {
            int cc = cb + wc * 64 + j * 16 + lrow;
            if (cc >= on && MODE == 0) { continue; }
            #pragma unroll
            for (int q = 0; q < 4; q++) {
                int rr = rrb + q;
                if (rr >= N_NODES) { continue; }
                if (MODE == 1) {
                    float sv = fmaxf(acc[i][j][q], 0.f) * (1.0f / 256.0f);
                    _Float16 hv = (_Float16)sv;
                    chi[(size_t)rr * 256 + cc] = hv;
                    clo[(size_t)rr * 256 + cc] = (_Float16)(sv - (float)hv);
                } else {
                    float v = acc[i][j][q] * inv;
                    if (bias != nullptr) { v += bias[cc]; }
                    cf[(size_t)rr * on + cc] = v;
                }
            }
        }
    }
}

// ---------------- order-statistic-pruned exact top-30, ties -> HIGHEST index ----------------
// 256 threads/row. thr = 30th-largest tile-max (exact superset bound) via rank.
// Collection over 4 waves; selection on wave 0. Fuses degrees (deg pre-zeroed
// by rownorm) AND the Adj row-zero (nontemporal; drains under selection).
__global__ __launch_bounds__(256) void topk_sel_kernel(float* __restrict__ S,
                                                       const float* __restrict__ TM,
                                                       float* __restrict__ tv,
                                                       int* __restrict__ ti,
                                                       float* __restrict__ deg) {
    __shared__ float cv[CANDCAP];
    __shared__ int ci[CANDCAP];
    __shared__ float tmv[NTILE];
    __shared__ int cntSh;
    __shared__ float thrSh;
    __shared__ float wv[4];
    __shared__ int wi[4];
    int t = threadIdx.x;
    int w = t >> 6;
    int lane = t & 63;
    int r = blockIdx.x;
    float* row = S + (size_t)r * N_NODES;
    const float* trow = TM + (size_t)r * 80;
    if (t == 0) { cntSh = 0; }
    if (t < NTILE) { tmv[t] = trow[t]; }
    __syncthreads();

    // thr by rank: lane ranks its <=2 tile-max values against all 79
    if (t < 64) {
        float v0 = tmv[lane];
        float v1 = (lane + 64 < NTILE) ? tmv[lane + 64] : -3.f;
        int rk0 = 0, rk1 = 0;
        for (int j = 0; j < NTILE; j++) {
            float vj = tmv[j];
            if (vj > v0 || (vj == v0 && j > lane)) { rk0++; }
            if (vj > v1 || (vj == v1 && j > lane + 64)) { rk1++; }
        }
        if (rk0 == KTOP - 1) { thrSh = v0; }
        if (lane + 64 < NTILE && rk1 == KTOP - 1) { thrSh = v1; }
    }
    __syncthreads();
    float thr = thrSh;

    // collection: wave w handles tiles w, w+4, ... (parallel, no insertion)
    for (int tt = w; tt < NTILE; tt += 4) {
        if (tmv[tt] < thr) { continue; }
        int c0 = tt * 128 + lane;
        int c1 = c0 + 64;
        float x0 = (c0 < N_NODES) ? row[c0] : -1.f;
        float x1 = (c1 < N_NODES) ? row[c1] : -1.f;
        if (x0 >= thr) {
            int p = atomicAdd(&cntSh, 1);
            if (p < CANDCAP) { cv[p] = x0; ci[p] = c0; }
        }
        if (x1 >= thr) {
            int p = atomicAdd(&cntSh, 1);
            if (p < CANDCAP) { cv[p] = x1; ci[p] = c1; }
        }
    }
    __syncthreads();
    int ncand = cntSh;
    bool fb = (ncand > CANDCAP) || (ncand < KTOP);

    if (fb) {
        // exact fallback over the intact row (value desc, index desc), 256t
        float rs = 0.f;
        for (int k = 0; k < KTOP; k++) {
            float bv = -1.f;
            int bi = -1;
            for (int j = t; j < N_NODES; j += 256) {
                float v = row[j];
                if (v >= bv) { bv = v; bi = j; }
            }
            #pragma unroll
            for (int off = 32; off > 0; off >>= 1) {
                float ov = __shfl_down(bv, off, 64);
                int oi = __shfl_down(bi, off, 64);
                if (ov > bv || (ov == bv && oi > bi)) { bv = ov; bi = oi; }
            }
            if (lane == 0) { wv[w] = bv; wi[w] = bi; }
            __syncthreads();
            if (t == 0) {
                float fv = wv[0];
                int fi = wi[0];
                for (int q = 1; q < 4; q++) {
                    if (wv[q] > fv || (wv[q] == fv && wi[q] > fi)) { fv = wv[q]; fi = wi[q]; }
                }
                tv[r * KTOP + k] = fv;
                ti[r * KTOP + k] = fi;
                atomicAdd(deg + fi, 0.5f * fv);
                rs += fv;
                row[fi] = -1.f;
            }
            __syncthreads();
        }
        if (t == 0) { atomicAdd(deg + r, 0.5f * rs); }
        // zero row after fallback selection (fused Adj-zero)
        f32x4 z = {0.f, 0.f, 0.f, 0.f};
        for (int u = t; u < NQ4; u += 256) {
            __builtin_nontemporal_store(z, (f32x4*)(row + 4 * u));
        }
        return;
    }

    // fused Adj-zero: wipe own row with all 256 threads (drains under selection)
    {
        f32x4 z = {0.f, 0.f, 0.f, 0.f};
        for (int u = t; u < NQ4; u += 256) {
            __builtin_nontemporal_store(z, (f32x4*)(row + 4 * u));
        }
    }

    // selection: wave 0 only, barrier-free (intra-wave LDS is program-ordered)
    if (t < 64) {
        float rs = 0.f;
        if (ncand <= 128) {
            float v0 = -2.f, v1 = -2.f;
            int i0 = -1, i1 = -1;
            if (lane < ncand) { v0 = cv[lane]; i0 = ci[lane]; }
            if (lane + 64 < ncand) { v1 = cv[lane + 64]; i1 = ci[lane + 64]; }
            for (int k = 0; k < KTOP; k++) {
                bool sel1 = (v1 > v0) || (v1 == v0 && i1 > i0);
                float bv = sel1 ? v1 : v0;
                int bi = sel1 ? i1 : i0;
                #pragma unroll
                for (int m = 32; m > 0; m >>= 1) {
                    float ov = __shfl_xor(bv, m, 64);
                    int oi = __shfl_xor(bi, m, 64);
                    if (ov > bv || (ov == bv && oi > bi)) { bv = ov; bi = oi; }
                }
                if (lane == 0) {
                    tv[r * KTOP + k] = bv;
                    ti[r * KTOP + k] = bi;
                    atomicAdd(deg + bi, 0.5f * bv);
                    rs += bv;
                }
                if (i0 == bi) { v0 = -2.f; }
                if (i1 == bi) { v1 = -2.f; }
            }
        } else {
            for (int k = 0; k < KTOP; k++) {
                float bv = -2.f;
                int bi = -1;
                int bq = -1;
                for (int q = lane; q < ncand; q += 64) {
                    float v = cv[q];
                    int idx = ci[q];
                    if (v > bv || (v == bv && idx > bi)) { bv = v; bi = idx; bq = q; }
                }
                #pragma unroll
                for (int m = 32; m > 0; m >>= 1) {
                    float ov = __shfl_xor(bv, m, 64);
                    int oi = __shfl_xor(bi, m, 64);
                    int oq = __shfl_xor(bq, m, 64);
                    if (ov > bv || (ov == bv && oi > bi)) { bv = ov; bi = oi; bq = oq; }
                }
                if (lane == 0) {
                    tv[r * KTOP + k] = bv;
                    ti[r * KTOP + k] = bi;
                    atomicAdd(deg + bi, 0.5f * bv);
                    rs += bv;
                    cv[bq] = -2.f;
                }
            }
        }
        if (lane == 0) { atomicAdd(deg + r, 0.5f * rs); }
    }
}

// ---------------- zero fill (fallback path only: CSR aliases Adj) ----------------
__global__ __launch_bounds__(256) void zero_fill(float4* __restrict__ p, unsigned int n4) {
    unsigned int i = blockIdx.x * 256u + threadIdx.x;
    unsigned int stride = gridDim.x * 256u;
    float4 z = {0.f, 0.f, 0.f, 0.f};
    for (; i < n4; i += stride) { p[i] = z; }
}

// ---------------- CSR build (+ optional fused dense Adj scatter); dis inlined ----------------
template<int WRITE_ADJ>
__global__ __launch_bounds__(256) void csr_adj(const float* __restrict__ tv,
                                               const int* __restrict__ ti,
                                               const float* __restrict__ deg,
                                               int* __restrict__ cnt,
                                               int* __restrict__ nbr,
                                               float* __restrict__ wgt,
                                               float* __restrict__ Adj) {
    int e = blockIdx.x * 256 + threadIdx.x;
    if (e >= N_NODES * KTOP) { return; }
    int i = e / KTOP;
    int j = ti[e];
    float v = tv[e];
    float vrev = 0.f;
    bool mutual = false;
    const int* tj = ti + (size_t)j * KTOP;
    const float* tvj = tv + (size_t)j * KTOP;
    for (int k = 0; k < KTOP; k++) {
        if (tj[k] == i) { vrev = tvj[k]; mutual = true; }
    }
    float dgi = deg[i];
    float dgj = deg[j];
    float di = dgi > 0.f ? 1.f / sqrtf(fmaxf(dgi, 1e-8f)) : 0.f;
    float dj = dgj > 0.f ? 1.f / sqrtf(fmaxf(dgj, 1e-8f)) : 0.f;
    float w = 0.5f * (v + vrev) * di * dj;
    int p = atomicAdd(cnt + i, 1);
    if (p < CAP) {
        nbr[(size_t)i * CAP + p] = j;
        wgt[(size_t)i * CAP + p] = w;
    }
    if (!mutual) {
        int p2 = atomicAdd(cnt + j, 1);
        if (p2 < CAP) {
            nbr[(size_t)j * CAP + p2] = i;
            wgt[(size_t)j * CAP + p2] = w;
        }
    }
    if (WRITE_ADJ) {
        Adj[(size_t)i * N_NODES + j] = w;
        Adj[(size_t)j * N_NODES + i] = w;
    }
}

// ---------------- Adj scatter (fallback path only); dis inlined ----------------
__global__ __launch_bounds__(256) void adj_scatter(const float* __restrict__ tv,
                                                   const int* __restrict__ ti,
                                                   const float* __restrict__ deg,
                                                   float* __restrict__ Adj) {
    int e = blockIdx.x * 256 + threadIdx.x;
    if (e >= N_NODES * KTOP) { return; }
    int i = e / KTOP;
    int j = ti[e];
    float v = tv[e];
    float vrev = 0.f;
    const int* tj = ti + (size_t)j * KTOP;
    const float* tvj = tv + (size_t)j * KTOP;
    for (int k = 0; k < KTOP; k++) {
        if (tj[k] == i) { vrev = tvj[k]; }
    }
    float dgi = deg[i];
    float dgj = deg[j];
    float di = dgi > 0.f ? 1.f / sqrtf(fmaxf(dgi, 1e-8f)) : 0.f;
    float dj = dgj > 0.f ? 1.f / sqrtf(fmaxf(dgj, 1e-8f)) : 0.f;
    float w = 0.5f * (v + vrev) * di * dj;
    Adj[(size_t)i * N_NODES + j] = w;
    Adj[(size_t)j * N_NODES + i] = w;
}

// ---------------- gather SpMM, 128 channels, relu fused (4x ILP) ----------------
__global__ __launch_bounds__(256) void gather128(const int* __restrict__ cnt,
                                                 const int* __restrict__ nbr,
                                                 const float* __restrict__ wgt,
                                                 const float* __restrict__ T,
                                                 float* __restrict__ Y) {
    int node = blockIdx.x * 2 + (threadIdx.x >> 7);
    int c = threadIdx.x & 127;
    if (node >= N_NODES) { return; }
    int n = cnt[node];
    if (n > CAP) { n = CAP; }
    const int* nb = nbr + (size_t)node * CAP;
    const float* wg = wgt + (size_t)node * CAP;
    float a0 = 0.f, a1 = 0.f, a2 = 0.f, a3 = 0.f;
    int k = 0;
    for (; k + 4 <= n; k += 4) {
        int4 j = *(const int4*)(nb + k);
        float4 w = *(const float4*)(wg + k);
        float t0 = T[(size_t)j.x * 128 + c];
        float t1 = T[(size_t)j.y * 128 + c];
        float t2 = T[(size_t)j.z * 128 + c];
        float t3 = T[(size_t)j.w * 128 + c];
        a0 = fmaf(w.x, t0, a0);
        a1 = fmaf(w.y, t1, a1);
        a2 = fmaf(w.z, t2, a2);
        a3 = fmaf(w.w, t3, a3);
    }
    for (; k < n; k++) { a0 = fmaf(wg[k], T[(size_t)nb[k] * 128 + c], a0); }
    float acc = (a0 + a1) + (a2 + a3);
    Y[(size_t)node * 128 + c] = fmaxf(acc, 0.f);
}

// ---------------- y1[M,128] @ Wg2[128,16] + bg2 -> t2[M,16] ----------------
__global__ __launch_bounds__(256) void gemm16(const float* __restrict__ y1,
                                              const float* __restrict__ Wg2,
                                              const float* __restrict__ bg2,
                                              float* __restrict__ out) {
    __shared__ float Ws[2048];
    __shared__ float Ys[16 * 132];
    int t = threadIdx.x;
    int n0 = blockIdx.x * 16;
    for (int i = t; i < 2048; i += 256) {
        Ws[i] = Wg2[i];
        int rr = i >> 7, cc = i & 127;
        int node = n0 + rr;
        if (node > N_NODES - 1) { node = N_NODES - 1; }
        Ys[rr * 132 + cc] = y1[(size_t)node * 128 + cc];
    }
    __syncthreads();
    int nn = t >> 4;
    int c = t & 15;
    int node = n0 + nn;
    if (node >= N_NODES) { return; }
    const float* yr = Ys + nn * 132;
    float acc = 0.f;
    #pragma unroll 4
    for (int k = 0; k < 128; k++) {
        acc = fmaf(yr[k], Ws[k * 16 + c], acc);
    }
    out[(size_t)node * 16 + c] = acc + bg2[c];
}

// ---------------- gather SpMM, 16 channels (4x ILP) ----------------
__global__ __launch_bounds__(256) void gather16(const int* __restrict__ cnt,
                                                const int* __restrict__ nbr,
                                                const float* __restrict__ wgt,
                                                const float* __restrict__ T,
                                                float* __restrict__ Y) {
    int node = blockIdx.x * 16 + (threadIdx.x >> 4);
    int c = threadIdx.x & 15;
    if (node >= N_NODES) { return; }
    int n = cnt[node];
    if (n > CAP) { n = CAP; }
    const int* nb = nbr + (size_t)node * CAP;
    const float* wg = wgt + (size_t)node * CAP;
    float a0 = 0.f, a1 = 0.f, a2 = 0.f, a3 = 0.f;
    int k = 0;
    for (; k + 4 <= n; k += 4) {
        int4 j = *(const int4*)(nb + k);
        float4 w = *(const float4*)(wg + k);
        float t0 = T[(size_t)j.x * 16 + c];
        float t1 = T[(size_t)j.y * 16 + c];
        float t2 = T[(size_t)j.z * 16 + c];
        float t3 = T[(size_t)j.w * 16 + c];
        a0 = fmaf(w.x, t0, a0);
        a1 = fmaf(w.y, t1, a1);
        a2 = fmaf(w.z, t2, a2);
        a3 = fmaf(w.w, t3, a3);
    }
    for (; k < n; k++) { a0 = fmaf(wg[k], T[(size_t)nb[k] * 16 + c], a0); }
    Y[(size_t)node * 16 + c] = (a0 + a1) + (a2 + a3);
}

extern "C" void kernel_launch(void* const* d_in, const int* in_sizes, int n_in,
                              void* d_out, int out_size, void* d_ws, size_t ws_size,
                              hipStream_t stream) {
    const float* features = (const float*)d_in[0];
    const float* x   = (const float*)d_in[1];
    const float* W1  = (const float*)d_in[2];
    const float* W2  = (const float*)d_in[3];
    const float* Wg1 = (const float*)d_in[4];
    const float* bg1 = (const float*)d_in[5];
    const float* Wg2 = (const float*)d_in[6];
    const float* bg2 = (const float*)d_in[7];

    float* ws = (float*)d_ws;
    // region A [0, 2.56M) floats: fsp -> hbuf -> tmax -> xsp
    // region B [2.56M, 5.12M) floats: h1sp -> Hhi/Hlo -> t1 | y1
    float* hbuf = ws;
    float* tmax = ws;                          // 800,000 f (10000 x 80), over dead hbuf
    float* tv   = ws + 5120000;               // 300,000 f
    int*   ti   = (int*)(ws + 5420000);       // 300,000 i
    float* deg  = ws + 5720000;               // 10,000 f
    int*   cnt  = (int*)(ws + 5730000);       // 10,000 i
    float* t2   = ws + 5740000;               // 160,000 f (W-splits live here early)
    float* t1   = ws + 2560000;               // Hhi region, after gemm_s dead
    float* y1   = ws + 3840000;               // Hlo region, after gemm_s dead

    _Float16* fsphi = (_Float16*)ws;
    _Float16* fsplo = fsphi + 2560000;
    _Float16* xsphi = (_Float16*)ws;                    // after tmax dead (post topk)
    _Float16* xsplo = xsphi + 2560000;
    _Float16* h1hi = (_Float16*)(ws + 2560000);
    _Float16* h1lo = h1hi + 2560000;
    _Float16* Hhi  = (_Float16*)(ws + 2560000);
    _Float16* Hlo  = Hhi + 2560000;
    _Float16* W1thi = (_Float16*)(ws + 5740000);        // 65,536 halves each
    _Float16* W1tlo = W1thi + 65536;
    _Float16* W2thi = W1thi + 131072;
    _Float16* W2tlo = W1thi + 196608;
    _Float16* Wg1thi = (_Float16*)(ws + 5740000);       // reuse after MLP chain (128x256)
    _Float16* Wg1tlo = Wg1thi + 32768;

    float* out_f = (float*)d_out;             // 160,000 f32
    float* Adj   = out_f + 160000;            // 1e8 f32 = 400 MB
    float* Sbuf  = Adj;                       // S until topk (topk zeroes it)

    // CSR placement: workspace if it fits, else alias Adj (zero+scatter at end)
    size_t csr_off = 5910000;                                  // floats
    size_t csr_need = (csr_off + (size_t)N_NODES * CAP * 2) * sizeof(float);
    bool csr_in_ws = ws_size >= csr_need;
    int*   nbr = csr_in_ws ? (int*)(ws + csr_off) : (int*)Adj;
    float* wgt = csr_in_ws ? (float*)(ws + csr_off + (size_t)N_NODES * CAP)
                           : (float*)(Adj + (size_t)N_NODES * CAP);

    // ---- splits (one launch) + MLP chain via fp16-split MFMA ----
    fused_split1<<<dim3(10512), dim3(256), 0, stream>>>(
        features, fsphi, fsplo, W1, W1thi, W1tlo, W2, W2thi, W2tlo);
    gemm_mlp<1><<<dim3(2, 79), dim3(256), 0, stream>>>(
        fsphi, fsplo, W1thi, W1tlo, h1hi, h1lo, (float*)nullptr, (const float*)nullptr, 256);
    gemm_mlp<0><<<dim3(2, 79), dim3(256), 0, stream>>>(
        h1hi, h1lo, W2thi, W2tlo, (_Float16*)nullptr, (_Float16*)nullptr, hbuf,
        (const float*)nullptr, 256);
    rownorm_np_kernel<<<dim3(N_NODES), dim3(256), 0, stream>>>(hbuf, Hhi, Hlo, deg, cnt);

    // ---- S (triangle, 1-D grid) + tile maxes; pruned exact top-30 + zero + degrees ----
    gemm_s_f16<<<dim3(NTRI), dim3(256), 0, stream>>>(Hhi, Hlo, Sbuf, tmax);
    topk_sel_kernel<<<dim3(N_NODES), dim3(256), 0, stream>>>(Sbuf, tmax, tv, ti, deg);

    // ---- x + Wg1 splits (one launch; tmax + W1t/W2t dead) + GCN layer-1 GEMM ----
    fused_split2<<<dim3(10128), dim3(256), 0, stream>>>(
        x, xsphi, xsplo, Wg1, Wg1thi, Wg1tlo);
    gemm_mlp<0><<<dim3(1, 79), dim3(256), 0, stream>>>(
        xsphi, xsplo, Wg1thi, Wg1tlo, (_Float16*)nullptr, (_Float16*)nullptr, t1, bg1, 128);

    // ---- CSR build (+ fused Adj scatter when CSR lives in ws; S zeroed by topk) ----
    int eblocks = (N_NODES * KTOP + 255) / 256;
    if (csr_in_ws) {
        csr_adj<1><<<dim3(eblocks), dim3(256), 0, stream>>>(tv, ti, deg, cnt, nbr, wgt, Adj);
    } else {
        csr_adj<0><<<dim3(eblocks), dim3(256), 0, stream>>>(tv, ti, deg, cnt, nbr, wgt, Adj);
    }

    // ---- GCN layers via gather SpMM ----
    gather128<<<dim3(N_NODES / 2), dim3(256), 0, stream>>>(cnt, nbr, wgt, t1, y1);
    gemm16<<<dim3(625), dim3(256), 0, stream>>>(y1, Wg2, bg2, t2);
    gather16<<<dim3((N_NODES + 15) / 16), dim3(256), 0, stream>>>(cnt, nbr, wgt, t2, out_f);

    // ---- fallback: CSR aliased Adj -> zero full Adj and scatter dense ----
    if (!csr_in_ws) {
        zero_fill<<<dim3(2048), dim3(256), 0, stream>>>(
            (float4*)Adj, (unsigned int)((size_t)N_NODES * N_NODES / 4));
        adj_scatter<<<dim3(eblocks), dim3(256), 0, stream>>>(tv, ti, deg, Adj);
    }
}